// Round 1
// baseline (890.017 us; speedup 1.0000x reference)
//
#include <hip/hip_runtime.h>
#include <cstdint>

// ODE Euler scan: B=1024, T=4096, S=8, E=8, H=32.
// One wave per batch element; 1024 blocks x 64 threads = 1 wave/SIMD.
// Model (R1-R6): solo wave issues 1 inst / 4 cyc -> duration ~= 4 * total
// insts. Measured 757us = ~111 insts/step vs ~63 ideal. R7 closes the
// codegen gap with guaranteed-width instructions:
//   - reduce32 x4 as ONE asm block: 20x v_add_f32_dpp (4 chains interleaved,
//     >=3-inst spacing covers the VALU->DPP wait-state hazard; s_nop guards
//     at block entry/exit) instead of unfused mov_dpp+add pairs.
//   - z-dot via v_pk_fma_f32/v_pk_mul_f32/v_pk_add_f32 asm (packed fp32).
//   - prefetch loads land directly in the outgoing EB (no stash movs).
//   - running byte offsets xoff/toff (+32/+4 per step, &4095 once per chunk).
//   - ysave latch (cmp+8 cndmask) -> LDS column write: addr cndmask + 4x
//     ds_write_b64 at 8B lane stride (conflict-free); non-latching lanes
//     write a dump region. Head reads 4x ds_read_b64 per chunk.
// Arithmetic is bit-identical to R6 (absmax 0.25 preserved).

typedef float v2f __attribute__((ext_vector_type(2)));

#define EXP2F(v) __builtin_amdgcn_exp2f(v)
#define RCPF(v) __builtin_amdgcn_rcpf(v)

__device__ __forceinline__ v2f pk_fma(v2f a, v2f b, v2f c) {
  asm("v_pk_fma_f32 %0, %1, %2, %0" : "+v"(c) : "v"(a), "v"(b));
  return c;
}
__device__ __forceinline__ v2f pk_mul(v2f a, v2f b) {
  v2f d;
  asm("v_pk_mul_f32 %0, %1, %2" : "=v"(d) : "v"(a), "v"(b));
  return d;
}
__device__ __forceinline__ v2f pk_add(v2f a, v2f b) {
  v2f d;
  asm("v_pk_add_f32 %0, %1, %2" : "=v"(d) : "v"(a), "v"(b));
  return d;
}

// 32-lane tree reduce on 4 values at once; results valid in lane 31 (half 0)
// and lane 63 (half 1). Same ctrl/mask sequence as R6's builtin path, fused
// to single v_add_f32_dpp per stage. Chains interleaved so each dependent
// same-register pair is 3 instructions apart (covers 2 wait states).
__device__ __forceinline__ void red4(float& p0, float& p1, float& p2, float& p3) {
  asm volatile(
      "s_nop 1\n\t"
      "v_add_f32_dpp %0, %0, %0 row_shr:1 row_mask:0xf bank_mask:0xf bound_ctrl:0\n\t"
      "v_add_f32_dpp %1, %1, %1 row_shr:1 row_mask:0xf bank_mask:0xf bound_ctrl:0\n\t"
      "v_add_f32_dpp %2, %2, %2 row_shr:1 row_mask:0xf bank_mask:0xf bound_ctrl:0\n\t"
      "v_add_f32_dpp %3, %3, %3 row_shr:1 row_mask:0xf bank_mask:0xf bound_ctrl:0\n\t"
      "v_add_f32_dpp %0, %0, %0 row_shr:2 row_mask:0xf bank_mask:0xf bound_ctrl:0\n\t"
      "v_add_f32_dpp %1, %1, %1 row_shr:2 row_mask:0xf bank_mask:0xf bound_ctrl:0\n\t"
      "v_add_f32_dpp %2, %2, %2 row_shr:2 row_mask:0xf bank_mask:0xf bound_ctrl:0\n\t"
      "v_add_f32_dpp %3, %3, %3 row_shr:2 row_mask:0xf bank_mask:0xf bound_ctrl:0\n\t"
      "v_add_f32_dpp %0, %0, %0 row_shr:4 row_mask:0xf bank_mask:0xf bound_ctrl:0\n\t"
      "v_add_f32_dpp %1, %1, %1 row_shr:4 row_mask:0xf bank_mask:0xf bound_ctrl:0\n\t"
      "v_add_f32_dpp %2, %2, %2 row_shr:4 row_mask:0xf bank_mask:0xf bound_ctrl:0\n\t"
      "v_add_f32_dpp %3, %3, %3 row_shr:4 row_mask:0xf bank_mask:0xf bound_ctrl:0\n\t"
      "v_add_f32_dpp %0, %0, %0 row_shr:8 row_mask:0xf bank_mask:0xf bound_ctrl:0\n\t"
      "v_add_f32_dpp %1, %1, %1 row_shr:8 row_mask:0xf bank_mask:0xf bound_ctrl:0\n\t"
      "v_add_f32_dpp %2, %2, %2 row_shr:8 row_mask:0xf bank_mask:0xf bound_ctrl:0\n\t"
      "v_add_f32_dpp %3, %3, %3 row_shr:8 row_mask:0xf bank_mask:0xf bound_ctrl:0\n\t"
      "v_add_f32_dpp %0, %0, %0 row_bcast:15 row_mask:0xa bank_mask:0xf bound_ctrl:0\n\t"
      "v_add_f32_dpp %1, %1, %1 row_bcast:15 row_mask:0xa bank_mask:0xf bound_ctrl:0\n\t"
      "v_add_f32_dpp %2, %2, %2 row_bcast:15 row_mask:0xa bank_mask:0xf bound_ctrl:0\n\t"
      "v_add_f32_dpp %3, %3, %3 row_bcast:15 row_mask:0xa bank_mask:0xf bound_ctrl:0\n\t"
      "s_nop 0"
      : "+v"(p0), "+v"(p1), "+v"(p2), "+v"(p3));
}

__device__ __forceinline__ float rdlane(float v, int lane) {
  return __int_as_float(__builtin_amdgcn_readlane(__float_as_int(v), lane));
}

__global__ __launch_bounds__(64, 1) void ode_scan_kernel(
    const float* __restrict__ x, const float* __restrict__ t,
    const float* __restrict__ y0, const float* __restrict__ Wr1,
    const float* __restrict__ br1, const float* __restrict__ Wr2,
    const float* __restrict__ br2, const float* __restrict__ W1,
    const float* __restrict__ b1, const float* __restrict__ W2,
    const float* __restrict__ b2, float* __restrict__ out) {
  constexpr int T = 4096;

  __shared__ __align__(16) float t_lds[4096];      // t, then dt in-place
  __shared__ __align__(16) float xbuf[2 * 64 * 8]; // double-buffered x chunks
  __shared__ float hw[112];                        // W1(80) b1(10) W2(20) b2(2)
  __shared__ __align__(8) float ysr[512];          // ysave: pair q at [q*128 + 2*l]
  __shared__ __align__(8) float ydump[512];        // write sink for non-latching lanes

  const int l = threadIdx.x;
  const int b = blockIdx.x;
  const int j = l & 31;     // owned hidden unit
  const int half = l >> 5;
  const int sq = half * 4;  // owned s-quad (half0: s0-3, half1: s4-7)

  // ---- stage t into LDS; dt in place (single-wave DS in-order) ----
  const float4* t4 = (const float4*)t;
  #pragma unroll
  for (int it = 0; it < 16; ++it) {
    float4 v = t4[it * 64 + l];
    *(float4*)&t_lds[(it * 64 + l) * 4] = v;
  }
  for (int it = 0; it < 64; ++it) {
    int i = it * 64 + l;
    float aa = t_lds[i];
    float cc = (i < T - 1) ? t_lds[i + 1] : 0.0f;
    t_lds[i] = cc - aa;  // slot 4095 garbage; never consumed
  }

  // ---- head weights into LDS ----
  for (int v = l; v < 112; v += 64) {
    float w;
    if (v < 80) w = W1[v];
    else if (v < 90) w = b1[v - 80];
    else if (v < 110) w = W2[v - 90];
    else w = b2[v - 110];
    hw[v] = w;
  }

  // ---- per-lane weights: pk pairs over the summation index ----
  v2f wy2[4], we2[4];
  #pragma unroll
  for (int q = 0; q < 4; ++q) {
    wy2[q].x = Wr1[(2 * q) * 32 + j];
    wy2[q].y = Wr1[(2 * q + 1) * 32 + j];
    we2[q].x = Wr1[(8 + 2 * q) * 32 + j];
    we2[q].y = Wr1[(8 + 2 * q + 1) * 32 + j];
  }
  float w2q[4], br2q[4];
  #pragma unroll
  for (int q = 0; q < 4; ++q) {
    w2q[q] = Wr2[j * 8 + sq + q];
    br2q[q] = (j == 0) ? br2[sq + q] : 0.0f;  // lane j==0 per half carries br2
  }
  v2f br1h; br1h.x = br1[j]; br1h.y = 0.0f;

  // ---- y state as 4 pairs, replicated in all lanes ----
  v2f y2[4];
  #pragma unroll
  for (int q = 0; q < 4; ++q) {
    y2[q].x = y0[b * 8 + 2 * q];
    y2[q].y = y0[b * 8 + 2 * q + 1];
  }

  // ysave column pointers (addresses constant per lane; select is 1 cndmask)
  float* const ysp_real = &ysr[2 * l];
  float* const ysp_dump = &ydump[2 * l];

  // prime slot 0 with y0 (lane 0 real, others dump)
  {
    float* yp = (l == 0) ? ysp_real : ysp_dump;
    *(v2f*)(yp + 0)   = y2[0];
    *(v2f*)(yp + 128) = y2[1];
    *(v2f*)(yp + 256) = y2[2];
    *(v2f*)(yp + 384) = y2[3];
  }

  // ---- stage x chunk 0 ----
  const float* xbase = x + (size_t)b * (T * 8);
  {
    float4 a0 = *(const float4*)&xbase[l * 8 + 0];
    float4 a1 = *(const float4*)&xbase[l * 8 + 4];
    *(float4*)&xbuf[l * 8 + 0] = a0;
    *(float4*)&xbuf[l * 8 + 4] = a1;
  }

  float2* out2 = (float2*)out + (size_t)b * T;

  // e/dt buffers: A/B manual double-buffer; ds_read destinations ARE the
  // next step's operands (no copies).
  struct EB { float4 a, b; float dt; };
  EB P, Q;
  P.a = *(const float4*)&xbuf[0];
  P.b = *(const float4*)&xbuf[4];
  P.dt = t_lds[0];

  // running byte offsets for the prefetch (inx = 1 next)
  uint32_t xoff = 32;  // (inx & 127) * 32
  uint32_t toff = 4;   // inx * 4

  #pragma unroll 1
  for (int c = 0; c < 64; ++c) {
    const bool more = (c < 63);
    float4 g0 = make_float4(0.f, 0.f, 0.f, 0.f), g1 = g0;
    if (more) {
      g0 = *(const float4*)&xbase[(c + 1) * 512 + l * 8 + 0];
      g1 = *(const float4*)&xbase[(c + 1) * 512 + l * 8 + 4];
    }

    // step: computes y_{c*64+k+1} consuming `in`; prefetches slot inx into
    // `o` directly; writes y pairs to ysave column (real for lane==kp1).
    auto step = [&](int kp1, const EB& in, EB& o) {
      // prefetch (lands in o's registers, consumed next step)
      o.a  = *(const float4*)((const char*)xbuf + xoff);
      o.b  = *(const float4*)((const char*)xbuf + (xoff + 16));
      o.dt = *(const float*)((const char*)t_lds + toff);
      xoff += 32;
      toff += 4;

      // z = br1 + e.We + y.Wy  (packed pairs over the summation index)
      v2f e01 = {in.a.x, in.a.y};
      v2f e23 = {in.a.z, in.a.w};
      v2f e45 = {in.b.x, in.b.y};
      v2f e67 = {in.b.z, in.b.w};
      v2f ze = pk_fma(e01, we2[0], br1h);
      ze = pk_fma(e23, we2[1], ze);
      ze = pk_fma(e45, we2[2], ze);
      ze = pk_fma(e67, we2[3], ze);
      v2f zy = pk_mul(y2[0], wy2[0]);
      zy = pk_fma(y2[1], wy2[1], zy);
      zy = pk_fma(y2[2], wy2[2], zy);
      zy = pk_fma(y2[3], wy2[3], zy);
      v2f z2 = pk_add(ze, zy);
      float z = z2.x + z2.y;

      // tanh(z) = 1 - 2/(exp2(2z*log2e)+1)
      float u = EXP2F(z * 2.885390081777927f);
      float rc = RCPF(u + 1.0f);
      float h = fmaf(-2.0f, rc, 1.0f);

      // partials (br2 rides on lane j==0) + fused 32-lane tree reduce
      float p0 = fmaf(h, w2q[0], br2q[0]);
      float p1 = fmaf(h, w2q[1], br2q[1]);
      float p2 = fmaf(h, w2q[2], br2q[2]);
      float p3 = fmaf(h, w2q[3], br2q[3]);
      red4(p0, p1, p2, p3);

      // y_s += dt * r_s   (r via readlane -> SGPR; v_fma v,s,v)
      float dtv = in.dt;
      y2[0].x = fmaf(rdlane(p0, 31), dtv, y2[0].x);
      y2[0].y = fmaf(rdlane(p1, 31), dtv, y2[0].y);
      y2[1].x = fmaf(rdlane(p2, 31), dtv, y2[1].x);
      y2[1].y = fmaf(rdlane(p3, 31), dtv, y2[1].y);
      y2[2].x = fmaf(rdlane(p0, 63), dtv, y2[2].x);
      y2[2].y = fmaf(rdlane(p1, 63), dtv, y2[2].y);
      y2[3].x = fmaf(rdlane(p2, 63), dtv, y2[3].x);
      y2[3].y = fmaf(rdlane(p3, 63), dtv, y2[3].y);

      // latch y_{inx} into LDS column kp1 (lane kp1 writes real, rest dump)
      float* yp = (l == kp1) ? ysp_real : ysp_dump;
      *(v2f*)(yp + 0)   = y2[0];
      *(v2f*)(yp + 128) = y2[1];
      *(v2f*)(yp + 256) = y2[2];
      *(v2f*)(yp + 384) = y2[3];
    };

    // first 4 pairs, then stage chunk c+1 (vmcnt has drained by then)
    #pragma unroll 1
    for (int kk = 0; kk < 8; kk += 2) { step(kk + 1, P, Q); step(kk + 2, Q, P); }
    if (more) {
      *(float4*)&xbuf[((c + 1) & 1) * 512 + l * 8 + 0] = g0;
      *(float4*)&xbuf[((c + 1) & 1) * 512 + l * 8 + 4] = g1;
    }
    #pragma unroll 1
    for (int kk = 8; kk < 62; kk += 2) { step(kk + 1, P, Q); step(kk + 2, Q, P); }
    step(63, P, Q);  // k = 62, latches lane 63

    // ---- head burst: lane l handles tau = c*64 + l, y from LDS column ----
    {
      float ys[8];
      #pragma unroll
      for (int q = 0; q < 4; ++q) {
        v2f yv = *(const v2f*)&ysr[q * 128 + 2 * l];
        ys[2 * q]     = yv.x;
        ys[2 * q + 1] = yv.y;
      }
      float o0 = hw[110], o1 = hw[111];
      #pragma unroll
      for (int m = 0; m < 10; ++m) {
        float hh = hw[80 + m];
        #pragma unroll
        for (int s = 0; s < 8; ++s) hh = fmaf(ys[s], hw[s * 10 + m], hh);
        hh = fmaxf(hh, 0.0f);
        o0 = fmaf(hh, hw[90 + m * 2 + 0], o0);
        o1 = fmaf(hh, hw[90 + m * 2 + 1], o1);
      }
      out2[c * 64 + l] = make_float2(o0, o1);
    }

    xoff &= 4095;                 // wrap at the chunk boundary (odd c)
    if (more) step(0, Q, P);      // k = 63: computes y_{(c+1)*64}, latches lane 0
  }
}

extern "C" void kernel_launch(void* const* d_in, const int* in_sizes, int n_in,
                              void* d_out, int out_size, void* d_ws, size_t ws_size,
                              hipStream_t stream) {
  const float* x   = (const float*)d_in[0];
  const float* t   = (const float*)d_in[1];
  const float* y0  = (const float*)d_in[2];
  const float* Wr1 = (const float*)d_in[3];
  const float* br1 = (const float*)d_in[4];
  const float* Wr2 = (const float*)d_in[5];
  const float* br2 = (const float*)d_in[6];
  const float* W1  = (const float*)d_in[7];
  const float* b1  = (const float*)d_in[8];
  const float* W2  = (const float*)d_in[9];
  const float* b2  = (const float*)d_in[10];
  (void)in_sizes; (void)n_in; (void)out_size; (void)d_ws; (void)ws_size;

  ode_scan_kernel<<<dim3(1024), dim3(64), 0, stream>>>(x, t, y0, Wr1, br1, Wr2,
                                                       br2, W1, b1, W2, b2,
                                                       (float*)d_out);
}

// Round 2
// 862.663 us; speedup vs baseline: 1.0317x; 1.0317x over previous
//
#include <hip/hip_runtime.h>
#include <cstdint>

// ODE Euler scan: B=1024, T=4096, S=8, E=8, H=32.
// One wave per batch element; 1024 blocks x 64 threads = 1 wave/SIMD.
// Model (R1-R6): solo wave issues 1 inst / 4 cyc -> duration ~= 4 * total
// insts. R7 post-mortem: pk/DPP fusion cut VALU insts (VALUBusy 70.8->55.1%)
// but the ysave LDS-column write added a per-step lgkmcnt stall on ds_write
// completion (+75 cyc/step non-VALU) -> net regression. R8 keeps the fused
// reduce + packed-fp32 dot + direct-to-EB prefetch + running offsets, and
// reverts ysave to the R6 register cndmask latch (pure VALU, no DS).
// Arithmetic is bit-identical to R6/R7 (absmax 0.25 preserved).

typedef float v2f __attribute__((ext_vector_type(2)));

#define EXP2F(v) __builtin_amdgcn_exp2f(v)
#define RCPF(v) __builtin_amdgcn_rcpf(v)

__device__ __forceinline__ v2f pk_fma(v2f a, v2f b, v2f c) {
  asm("v_pk_fma_f32 %0, %1, %2, %0" : "+v"(c) : "v"(a), "v"(b));
  return c;
}
__device__ __forceinline__ v2f pk_mul(v2f a, v2f b) {
  v2f d;
  asm("v_pk_mul_f32 %0, %1, %2" : "=v"(d) : "v"(a), "v"(b));
  return d;
}
__device__ __forceinline__ v2f pk_add(v2f a, v2f b) {
  v2f d;
  asm("v_pk_add_f32 %0, %1, %2" : "=v"(d) : "v"(a), "v"(b));
  return d;
}

// 32-lane tree reduce on 4 values at once; results valid in lane 31 (half 0)
// and lane 63 (half 1). Fused v_add_f32_dpp per stage; chains interleaved so
// each dependent same-register pair is 4 instructions apart (covers the 2
// VALU->DPP wait states). Entry s_nop 1 guards the case where the scheduler
// places a partial's fma immediately before the block. No exit guard: the
// first consumer (readlane p0) is >=4 insts after p0's last DPP write.
__device__ __forceinline__ void red4(float& p0, float& p1, float& p2, float& p3) {
  asm volatile(
      "s_nop 1\n\t"
      "v_add_f32_dpp %0, %0, %0 row_shr:1 row_mask:0xf bank_mask:0xf bound_ctrl:0\n\t"
      "v_add_f32_dpp %1, %1, %1 row_shr:1 row_mask:0xf bank_mask:0xf bound_ctrl:0\n\t"
      "v_add_f32_dpp %2, %2, %2 row_shr:1 row_mask:0xf bank_mask:0xf bound_ctrl:0\n\t"
      "v_add_f32_dpp %3, %3, %3 row_shr:1 row_mask:0xf bank_mask:0xf bound_ctrl:0\n\t"
      "v_add_f32_dpp %0, %0, %0 row_shr:2 row_mask:0xf bank_mask:0xf bound_ctrl:0\n\t"
      "v_add_f32_dpp %1, %1, %1 row_shr:2 row_mask:0xf bank_mask:0xf bound_ctrl:0\n\t"
      "v_add_f32_dpp %2, %2, %2 row_shr:2 row_mask:0xf bank_mask:0xf bound_ctrl:0\n\t"
      "v_add_f32_dpp %3, %3, %3 row_shr:2 row_mask:0xf bank_mask:0xf bound_ctrl:0\n\t"
      "v_add_f32_dpp %0, %0, %0 row_shr:4 row_mask:0xf bank_mask:0xf bound_ctrl:0\n\t"
      "v_add_f32_dpp %1, %1, %1 row_shr:4 row_mask:0xf bank_mask:0xf bound_ctrl:0\n\t"
      "v_add_f32_dpp %2, %2, %2 row_shr:4 row_mask:0xf bank_mask:0xf bound_ctrl:0\n\t"
      "v_add_f32_dpp %3, %3, %3 row_shr:4 row_mask:0xf bank_mask:0xf bound_ctrl:0\n\t"
      "v_add_f32_dpp %0, %0, %0 row_shr:8 row_mask:0xf bank_mask:0xf bound_ctrl:0\n\t"
      "v_add_f32_dpp %1, %1, %1 row_shr:8 row_mask:0xf bank_mask:0xf bound_ctrl:0\n\t"
      "v_add_f32_dpp %2, %2, %2 row_shr:8 row_mask:0xf bank_mask:0xf bound_ctrl:0\n\t"
      "v_add_f32_dpp %3, %3, %3 row_shr:8 row_mask:0xf bank_mask:0xf bound_ctrl:0\n\t"
      "v_add_f32_dpp %0, %0, %0 row_bcast:15 row_mask:0xa bank_mask:0xf bound_ctrl:0\n\t"
      "v_add_f32_dpp %1, %1, %1 row_bcast:15 row_mask:0xa bank_mask:0xf bound_ctrl:0\n\t"
      "v_add_f32_dpp %2, %2, %2 row_bcast:15 row_mask:0xa bank_mask:0xf bound_ctrl:0\n\t"
      "v_add_f32_dpp %3, %3, %3 row_bcast:15 row_mask:0xa bank_mask:0xf bound_ctrl:0"
      : "+v"(p0), "+v"(p1), "+v"(p2), "+v"(p3));
}

__device__ __forceinline__ float rdlane(float v, int lane) {
  return __int_as_float(__builtin_amdgcn_readlane(__float_as_int(v), lane));
}

__global__ __launch_bounds__(64, 1) void ode_scan_kernel(
    const float* __restrict__ x, const float* __restrict__ t,
    const float* __restrict__ y0, const float* __restrict__ Wr1,
    const float* __restrict__ br1, const float* __restrict__ Wr2,
    const float* __restrict__ br2, const float* __restrict__ W1,
    const float* __restrict__ b1, const float* __restrict__ W2,
    const float* __restrict__ b2, float* __restrict__ out) {
  constexpr int T = 4096;

  __shared__ __align__(16) float t_lds[4096];      // t, then dt in-place
  __shared__ __align__(16) float xbuf[2 * 64 * 8]; // double-buffered x chunks
  __shared__ float hw[112];                        // W1(80) b1(10) W2(20) b2(2)

  const int l = threadIdx.x;
  const int b = blockIdx.x;
  const int j = l & 31;     // owned hidden unit
  const int half = l >> 5;
  const int sq = half * 4;  // owned s-quad (half0: s0-3, half1: s4-7)

  // ---- stage t into LDS; dt in place (single-wave DS in-order) ----
  const float4* t4 = (const float4*)t;
  #pragma unroll
  for (int it = 0; it < 16; ++it) {
    float4 v = t4[it * 64 + l];
    *(float4*)&t_lds[(it * 64 + l) * 4] = v;
  }
  for (int it = 0; it < 64; ++it) {
    int i = it * 64 + l;
    float aa = t_lds[i];
    float cc = (i < T - 1) ? t_lds[i + 1] : 0.0f;
    t_lds[i] = cc - aa;  // slot 4095 garbage; never consumed
  }

  // ---- head weights into LDS ----
  for (int v = l; v < 112; v += 64) {
    float w;
    if (v < 80) w = W1[v];
    else if (v < 90) w = b1[v - 80];
    else if (v < 110) w = W2[v - 90];
    else w = b2[v - 110];
    hw[v] = w;
  }

  // ---- per-lane weights: pk pairs over the summation index ----
  v2f wy2[4], we2[4];
  #pragma unroll
  for (int q = 0; q < 4; ++q) {
    wy2[q].x = Wr1[(2 * q) * 32 + j];
    wy2[q].y = Wr1[(2 * q + 1) * 32 + j];
    we2[q].x = Wr1[(8 + 2 * q) * 32 + j];
    we2[q].y = Wr1[(8 + 2 * q + 1) * 32 + j];
  }
  float w2q[4], br2q[4];
  #pragma unroll
  for (int q = 0; q < 4; ++q) {
    w2q[q] = Wr2[j * 8 + sq + q];
    br2q[q] = (j == 0) ? br2[sq + q] : 0.0f;  // lane j==0 per half carries br2
  }
  v2f br1h; br1h.x = br1[j]; br1h.y = 0.0f;

  // ---- y state as 4 pairs, replicated in all lanes; ysave latch in regs ----
  v2f y2[4], ysv[4];
  #pragma unroll
  for (int q = 0; q < 4; ++q) {
    y2[q].x = y0[b * 8 + 2 * q];
    y2[q].y = y0[b * 8 + 2 * q + 1];
    ysv[q] = y2[q];  // lane 0's tau=0 prime (other lanes latched before use)
  }

  // ---- stage x chunk 0 ----
  const float* xbase = x + (size_t)b * (T * 8);
  {
    float4 a0 = *(const float4*)&xbase[l * 8 + 0];
    float4 a1 = *(const float4*)&xbase[l * 8 + 4];
    *(float4*)&xbuf[l * 8 + 0] = a0;
    *(float4*)&xbuf[l * 8 + 4] = a1;
  }

  float2* out2 = (float2*)out + (size_t)b * T;

  // e/dt buffers: A/B manual double-buffer; ds_read destinations ARE the
  // next step's operands (no copies).
  struct EB { float4 a, b; float dt; };
  EB P, Q;
  P.a = *(const float4*)&xbuf[0];
  P.b = *(const float4*)&xbuf[4];
  P.dt = t_lds[0];

  // running byte offsets for the prefetch (inx = 1 next)
  uint32_t xoff = 32;  // (inx & 127) * 32
  uint32_t toff = 4;   // inx * 4

  #pragma unroll 1
  for (int c = 0; c < 64; ++c) {
    const bool more = (c < 63);
    float4 g0 = make_float4(0.f, 0.f, 0.f, 0.f), g1 = g0;
    if (more) {
      g0 = *(const float4*)&xbase[(c + 1) * 512 + l * 8 + 0];
      g1 = *(const float4*)&xbase[(c + 1) * 512 + l * 8 + 4];
    }

    // step: computes y_{c*64 + kp1} consuming `in`; prefetches the next slot
    // directly into `o`; latches lane kp1's ysave (pure VALU cndmask).
    auto step = [&](int kp1, const EB& in, EB& o) {
      // prefetch (lands in o's registers, consumed next step)
      o.a  = *(const float4*)((const char*)xbuf + xoff);
      o.b  = *(const float4*)((const char*)xbuf + (xoff + 16));
      o.dt = *(const float*)((const char*)t_lds + toff);
      xoff += 32;
      toff += 4;

      // z = br1 + e.We + y.Wy  (packed pairs over the summation index)
      v2f e01 = {in.a.x, in.a.y};
      v2f e23 = {in.a.z, in.a.w};
      v2f e45 = {in.b.x, in.b.y};
      v2f e67 = {in.b.z, in.b.w};
      v2f ze = pk_fma(e01, we2[0], br1h);
      ze = pk_fma(e23, we2[1], ze);
      ze = pk_fma(e45, we2[2], ze);
      ze = pk_fma(e67, we2[3], ze);
      v2f zy = pk_mul(y2[0], wy2[0]);
      zy = pk_fma(y2[1], wy2[1], zy);
      zy = pk_fma(y2[2], wy2[2], zy);
      zy = pk_fma(y2[3], wy2[3], zy);
      v2f z2 = pk_add(ze, zy);
      float z = z2.x + z2.y;

      // tanh(z) = 1 - 2/(exp2(2z*log2e)+1)
      float u = EXP2F(z * 2.885390081777927f);
      float rc = RCPF(u + 1.0f);
      float h = fmaf(-2.0f, rc, 1.0f);

      // partials (br2 rides on lane j==0) + fused 32-lane tree reduce
      float p0 = fmaf(h, w2q[0], br2q[0]);
      float p1 = fmaf(h, w2q[1], br2q[1]);
      float p2 = fmaf(h, w2q[2], br2q[2]);
      float p3 = fmaf(h, w2q[3], br2q[3]);
      red4(p0, p1, p2, p3);

      // y_s += dt * r_s   (r via readlane -> SGPR; v_fma v,s,v)
      float dtv = in.dt;
      y2[0].x = fmaf(rdlane(p0, 31), dtv, y2[0].x);
      y2[0].y = fmaf(rdlane(p1, 31), dtv, y2[0].y);
      y2[1].x = fmaf(rdlane(p2, 31), dtv, y2[1].x);
      y2[1].y = fmaf(rdlane(p3, 31), dtv, y2[1].y);
      y2[2].x = fmaf(rdlane(p0, 63), dtv, y2[2].x);
      y2[2].y = fmaf(rdlane(p1, 63), dtv, y2[2].y);
      y2[3].x = fmaf(rdlane(p2, 63), dtv, y2[3].x);
      y2[3].y = fmaf(rdlane(p3, 63), dtv, y2[3].y);

      // latch y into lane kp1's ysave (pure VALU cndmask; no DS traffic)
      const bool pr = (l == kp1);
      ysv[0].x = pr ? y2[0].x : ysv[0].x;
      ysv[0].y = pr ? y2[0].y : ysv[0].y;
      ysv[1].x = pr ? y2[1].x : ysv[1].x;
      ysv[1].y = pr ? y2[1].y : ysv[1].y;
      ysv[2].x = pr ? y2[2].x : ysv[2].x;
      ysv[2].y = pr ? y2[2].y : ysv[2].y;
      ysv[3].x = pr ? y2[3].x : ysv[3].x;
      ysv[3].y = pr ? y2[3].y : ysv[3].y;
    };

    // first 4 pairs, then stage chunk c+1 (vmcnt has drained by then)
    #pragma unroll 1
    for (int kk = 0; kk < 8; kk += 2) { step(kk + 1, P, Q); step(kk + 2, Q, P); }
    if (more) {
      *(float4*)&xbuf[((c + 1) & 1) * 512 + l * 8 + 0] = g0;
      *(float4*)&xbuf[((c + 1) & 1) * 512 + l * 8 + 4] = g1;
    }
    #pragma unroll 1
    for (int kk = 8; kk < 62; kk += 2) { step(kk + 1, P, Q); step(kk + 2, Q, P); }
    step(63, P, Q);  // k = 62, latches lane 63

    // ---- head burst: lane l handles tau = c*64 + l, y from register ysave ----
    {
      float ys[8] = {ysv[0].x, ysv[0].y, ysv[1].x, ysv[1].y,
                     ysv[2].x, ysv[2].y, ysv[3].x, ysv[3].y};
      float o0 = hw[110], o1 = hw[111];
      #pragma unroll
      for (int m = 0; m < 10; ++m) {
        float hh = hw[80 + m];
        #pragma unroll
        for (int s = 0; s < 8; ++s) hh = fmaf(ys[s], hw[s * 10 + m], hh);
        hh = fmaxf(hh, 0.0f);
        o0 = fmaf(hh, hw[90 + m * 2 + 0], o0);
        o1 = fmaf(hh, hw[90 + m * 2 + 1], o1);
      }
      out2[c * 64 + l] = make_float2(o0, o1);
    }

    xoff &= 4095;                 // wrap at the chunk boundary (odd c)
    if (more) step(0, Q, P);      // k = 63: computes y_{(c+1)*64}, latches lane 0
  }
}

extern "C" void kernel_launch(void* const* d_in, const int* in_sizes, int n_in,
                              void* d_out, int out_size, void* d_ws, size_t ws_size,
                              hipStream_t stream) {
  const float* x   = (const float*)d_in[0];
  const float* t   = (const float*)d_in[1];
  const float* y0  = (const float*)d_in[2];
  const float* Wr1 = (const float*)d_in[3];
  const float* br1 = (const float*)d_in[4];
  const float* Wr2 = (const float*)d_in[5];
  const float* br2 = (const float*)d_in[6];
  const float* W1  = (const float*)d_in[7];
  const float* b1  = (const float*)d_in[8];
  const float* W2  = (const float*)d_in[9];
  const float* b2  = (const float*)d_in[10];
  (void)in_sizes; (void)n_in; (void)out_size; (void)d_ws; (void)ws_size;

  ode_scan_kernel<<<dim3(1024), dim3(64), 0, stream>>>(x, t, y0, Wr1, br1, Wr2,
                                                       br2, W1, b1, W2, b2,
                                                       (float*)d_out);
}

// Round 4
// 846.902 us; speedup vs baseline: 1.0509x; 1.0186x over previous
//
#include <hip/hip_runtime.h>
#include <cstdint>

// ODE Euler scan: B=1024, T=4096, S=8, E=8, H=32.
// One wave per batch element; 1024 blocks x 64 threads = 1 wave/SIMD.
// R8 post-mortem: duration invariant (443/455/452 cyc/step) under a
// ~35-inst/step swing -> the loop is DEPENDENCY-CHAIN-bound at ~450 cyc,
// ~19 links x ~20-24 cyc/link (solo-wave dependent-issue turnaround).
// R9 cuts 3 chain links with negligible inst delta:
//   - dot tree with e-side seeds: zeA..D computed off-chain from prefetched
//     e; y-side = 4 parallel pk_fma into the seeds + 2 pk_add levels.
//     y->z depth 6 -> 4.
//   - p-fold: p_q = fma(-2*w2q, rc, w2q+br2q) with both coefficients
//     precomputed; removes the h link (head never needs h).
// red4 stays: 20 DPP insts is the issue floor for a 4-value 32-lane reduce
// (VOP3P has no DPP); readlane path kept (alternatives cost >= chain).
// (R9 resubmission: previous round was an infra failure, no data.)

typedef float v2f __attribute__((ext_vector_type(2)));

#define EXP2F(v) __builtin_amdgcn_exp2f(v)
#define RCPF(v) __builtin_amdgcn_rcpf(v)

__device__ __forceinline__ v2f pk_fma(v2f a, v2f b, v2f c) {
  asm("v_pk_fma_f32 %0, %1, %2, %0" : "+v"(c) : "v"(a), "v"(b));
  return c;
}
__device__ __forceinline__ v2f pk_mul(v2f a, v2f b) {
  v2f d;
  asm("v_pk_mul_f32 %0, %1, %2" : "=v"(d) : "v"(a), "v"(b));
  return d;
}
__device__ __forceinline__ v2f pk_add(v2f a, v2f b) {
  v2f d;
  asm("v_pk_add_f32 %0, %1, %2" : "=v"(d) : "v"(a), "v"(b));
  return d;
}

// 32-lane tree reduce on 4 values at once; results valid in lane 31 (half 0)
// and lane 63 (half 1). Fused v_add_f32_dpp per stage; chains interleaved so
// each dependent same-register pair is 4 instructions apart (covers the 2
// VALU->DPP wait states). Entry s_nop 1 guards a possibly-adjacent p-fma.
__device__ __forceinline__ void red4(float& p0, float& p1, float& p2, float& p3) {
  asm volatile(
      "s_nop 1\n\t"
      "v_add_f32_dpp %0, %0, %0 row_shr:1 row_mask:0xf bank_mask:0xf bound_ctrl:0\n\t"
      "v_add_f32_dpp %1, %1, %1 row_shr:1 row_mask:0xf bank_mask:0xf bound_ctrl:0\n\t"
      "v_add_f32_dpp %2, %2, %2 row_shr:1 row_mask:0xf bank_mask:0xf bound_ctrl:0\n\t"
      "v_add_f32_dpp %3, %3, %3 row_shr:1 row_mask:0xf bank_mask:0xf bound_ctrl:0\n\t"
      "v_add_f32_dpp %0, %0, %0 row_shr:2 row_mask:0xf bank_mask:0xf bound_ctrl:0\n\t"
      "v_add_f32_dpp %1, %1, %1 row_shr:2 row_mask:0xf bank_mask:0xf bound_ctrl:0\n\t"
      "v_add_f32_dpp %2, %2, %2 row_shr:2 row_mask:0xf bank_mask:0xf bound_ctrl:0\n\t"
      "v_add_f32_dpp %3, %3, %3 row_shr:2 row_mask:0xf bank_mask:0xf bound_ctrl:0\n\t"
      "v_add_f32_dpp %0, %0, %0 row_shr:4 row_mask:0xf bank_mask:0xf bound_ctrl:0\n\t"
      "v_add_f32_dpp %1, %1, %1 row_shr:4 row_mask:0xf bank_mask:0xf bound_ctrl:0\n\t"
      "v_add_f32_dpp %2, %2, %2 row_shr:4 row_mask:0xf bank_mask:0xf bound_ctrl:0\n\t"
      "v_add_f32_dpp %3, %3, %3 row_shr:4 row_mask:0xf bank_mask:0xf bound_ctrl:0\n\t"
      "v_add_f32_dpp %0, %0, %0 row_shr:8 row_mask:0xf bank_mask:0xf bound_ctrl:0\n\t"
      "v_add_f32_dpp %1, %1, %1 row_shr:8 row_mask:0xf bank_mask:0xf bound_ctrl:0\n\t"
      "v_add_f32_dpp %2, %2, %2 row_shr:8 row_mask:0xf bank_mask:0xf bound_ctrl:0\n\t"
      "v_add_f32_dpp %3, %3, %3 row_shr:8 row_mask:0xf bank_mask:0xf bound_ctrl:0\n\t"
      "v_add_f32_dpp %0, %0, %0 row_bcast:15 row_mask:0xa bank_mask:0xf bound_ctrl:0\n\t"
      "v_add_f32_dpp %1, %1, %1 row_bcast:15 row_mask:0xa bank_mask:0xf bound_ctrl:0\n\t"
      "v_add_f32_dpp %2, %2, %2 row_bcast:15 row_mask:0xa bank_mask:0xf bound_ctrl:0\n\t"
      "v_add_f32_dpp %3, %3, %3 row_bcast:15 row_mask:0xa bank_mask:0xf bound_ctrl:0"
      : "+v"(p0), "+v"(p1), "+v"(p2), "+v"(p3));
}

__device__ __forceinline__ float rdlane(float v, int lane) {
  return __int_as_float(__builtin_amdgcn_readlane(__float_as_int(v), lane));
}

__global__ __launch_bounds__(64, 1) void ode_scan_kernel(
    const float* __restrict__ x, const float* __restrict__ t,
    const float* __restrict__ y0, const float* __restrict__ Wr1,
    const float* __restrict__ br1, const float* __restrict__ Wr2,
    const float* __restrict__ br2, const float* __restrict__ W1,
    const float* __restrict__ b1, const float* __restrict__ W2,
    const float* __restrict__ b2, float* __restrict__ out) {
  constexpr int T = 4096;

  __shared__ __align__(16) float t_lds[4096];      // t, then dt in-place
  __shared__ __align__(16) float xbuf[2 * 64 * 8]; // double-buffered x chunks
  __shared__ float hw[112];                        // W1(80) b1(10) W2(20) b2(2)

  const int l = threadIdx.x;
  const int b = blockIdx.x;
  const int j = l & 31;     // owned hidden unit
  const int half = l >> 5;
  const int sq = half * 4;  // owned s-quad (half0: s0-3, half1: s4-7)

  // ---- stage t into LDS; dt in place (single-wave DS in-order) ----
  const float4* t4 = (const float4*)t;
  #pragma unroll
  for (int it = 0; it < 16; ++it) {
    float4 v = t4[it * 64 + l];
    *(float4*)&t_lds[(it * 64 + l) * 4] = v;
  }
  for (int it = 0; it < 64; ++it) {
    int i = it * 64 + l;
    float aa = t_lds[i];
    float cc = (i < T - 1) ? t_lds[i + 1] : 0.0f;
    t_lds[i] = cc - aa;  // slot 4095 garbage; never consumed
  }

  // ---- head weights into LDS ----
  for (int v = l; v < 112; v += 64) {
    float w;
    if (v < 80) w = W1[v];
    else if (v < 90) w = b1[v - 80];
    else if (v < 110) w = W2[v - 90];
    else w = b2[v - 110];
    hw[v] = w;
  }

  // ---- per-lane weights: pk pairs over the summation index ----
  v2f wy2[4], we2[4];
  #pragma unroll
  for (int q = 0; q < 4; ++q) {
    wy2[q].x = Wr1[(2 * q) * 32 + j];
    wy2[q].y = Wr1[(2 * q + 1) * 32 + j];
    we2[q].x = Wr1[(8 + 2 * q) * 32 + j];
    we2[q].y = Wr1[(8 + 2 * q + 1) * 32 + j];
  }
  // p-fold coefficients: p_q = w2*h + br2 = fma(-2*w2, rc, w2 + br2)
  float m2w2[4], wpb[4];
  #pragma unroll
  for (int q = 0; q < 4; ++q) {
    float w = Wr2[j * 8 + sq + q];
    float bb = (j == 0) ? br2[sq + q] : 0.0f;  // lane j==0 per half carries br2
    m2w2[q] = -2.0f * w;
    wpb[q] = w + bb;
  }
  v2f br1h; br1h.x = br1[j]; br1h.y = 0.0f;

  // ---- y state as 4 pairs, replicated in all lanes; ysave latch in regs ----
  v2f y2[4], ysv[4];
  #pragma unroll
  for (int q = 0; q < 4; ++q) {
    y2[q].x = y0[b * 8 + 2 * q];
    y2[q].y = y0[b * 8 + 2 * q + 1];
    ysv[q] = y2[q];  // lane 0's tau=0 prime (other lanes latched before use)
  }

  // ---- stage x chunk 0 ----
  const float* xbase = x + (size_t)b * (T * 8);
  {
    float4 a0 = *(const float4*)&xbase[l * 8 + 0];
    float4 a1 = *(const float4*)&xbase[l * 8 + 4];
    *(float4*)&xbuf[l * 8 + 0] = a0;
    *(float4*)&xbuf[l * 8 + 4] = a1;
  }

  float2* out2 = (float2*)out + (size_t)b * T;

  // e/dt buffers: A/B manual double-buffer; ds_read destinations ARE the
  // next step's operands (no copies).
  struct EB { float4 a, b; float dt; };
  EB P, Q;
  P.a = *(const float4*)&xbuf[0];
  P.b = *(const float4*)&xbuf[4];
  P.dt = t_lds[0];

  // running byte offsets for the prefetch (inx = 1 next)
  uint32_t xoff = 32;  // (inx & 127) * 32
  uint32_t toff = 4;   // inx * 4

  #pragma unroll 1
  for (int c = 0; c < 64; ++c) {
    const bool more = (c < 63);
    float4 g0 = make_float4(0.f, 0.f, 0.f, 0.f), g1 = g0;
    if (more) {
      g0 = *(const float4*)&xbase[(c + 1) * 512 + l * 8 + 0];
      g1 = *(const float4*)&xbase[(c + 1) * 512 + l * 8 + 4];
    }

    // step: computes y_{c*64 + kp1} consuming `in`; prefetches the next slot
    // directly into `o`; latches lane kp1's ysave (pure VALU cndmask).
    auto step = [&](int kp1, const EB& in, EB& o) {
      // prefetch (lands in o's registers, consumed next step)
      o.a  = *(const float4*)((const char*)xbuf + xoff);
      o.b  = *(const float4*)((const char*)xbuf + (xoff + 16));
      o.dt = *(const float*)((const char*)t_lds + toff);
      xoff += 32;
      toff += 4;

      // e-side seeds: off the y-chain (e was prefetched a full step early)
      v2f e01 = {in.a.x, in.a.y};
      v2f e23 = {in.a.z, in.a.w};
      v2f e45 = {in.b.x, in.b.y};
      v2f e67 = {in.b.z, in.b.w};
      v2f zeA = pk_fma(e01, we2[0], br1h);
      v2f zeB = pk_mul(e23, we2[1]);
      v2f zeC = pk_mul(e45, we2[2]);
      v2f zeD = pk_mul(e67, we2[3]);

      // y-chain: 4 parallel pk_fma into the seeds, 2 pk_add levels, scalar add
      v2f a0 = pk_fma(y2[0], wy2[0], zeA);
      v2f a1 = pk_fma(y2[1], wy2[1], zeB);
      v2f a2 = pk_fma(y2[2], wy2[2], zeC);
      v2f a3 = pk_fma(y2[3], wy2[3], zeD);
      v2f s01 = pk_add(a0, a1);
      v2f s23 = pk_add(a2, a3);
      v2f g = pk_add(s01, s23);
      float z = g.x + g.y;

      // tanh folded into p: rc = 1/(exp2(2z*log2e)+1);
      // p_q = w2q*(1-2rc) + br2q = fma(-2*w2q, rc, w2q+br2q)
      float u = EXP2F(z * 2.885390081777927f);
      float rc = RCPF(u + 1.0f);
      float p0 = fmaf(m2w2[0], rc, wpb[0]);
      float p1 = fmaf(m2w2[1], rc, wpb[1]);
      float p2 = fmaf(m2w2[2], rc, wpb[2]);
      float p3 = fmaf(m2w2[3], rc, wpb[3]);
      red4(p0, p1, p2, p3);

      // y_s += dt * r_s   (r via readlane -> SGPR; v_fma v,s,v)
      float dtv = in.dt;
      y2[0].x = fmaf(rdlane(p0, 31), dtv, y2[0].x);
      y2[0].y = fmaf(rdlane(p1, 31), dtv, y2[0].y);
      y2[1].x = fmaf(rdlane(p2, 31), dtv, y2[1].x);
      y2[1].y = fmaf(rdlane(p3, 31), dtv, y2[1].y);
      y2[2].x = fmaf(rdlane(p0, 63), dtv, y2[2].x);
      y2[2].y = fmaf(rdlane(p1, 63), dtv, y2[2].y);
      y2[3].x = fmaf(rdlane(p2, 63), dtv, y2[3].x);
      y2[3].y = fmaf(rdlane(p3, 63), dtv, y2[3].y);

      // latch y into lane kp1's ysave (pure VALU cndmask; no DS traffic)
      const bool pr = (l == kp1);
      ysv[0].x = pr ? y2[0].x : ysv[0].x;
      ysv[0].y = pr ? y2[0].y : ysv[0].y;
      ysv[1].x = pr ? y2[1].x : ysv[1].x;
      ysv[1].y = pr ? y2[1].y : ysv[1].y;
      ysv[2].x = pr ? y2[2].x : ysv[2].x;
      ysv[2].y = pr ? y2[2].y : ysv[2].y;
      ysv[3].x = pr ? y2[3].x : ysv[3].x;
      ysv[3].y = pr ? y2[3].y : ysv[3].y;
    };

    // first 4 pairs, then stage chunk c+1 (vmcnt has drained by then)
    #pragma unroll 1
    for (int kk = 0; kk < 8; kk += 2) { step(kk + 1, P, Q); step(kk + 2, Q, P); }
    if (more) {
      *(float4*)&xbuf[((c + 1) & 1) * 512 + l * 8 + 0] = g0;
      *(float4*)&xbuf[((c + 1) & 1) * 512 + l * 8 + 4] = g1;
    }
    #pragma unroll 1
    for (int kk = 8; kk < 62; kk += 2) { step(kk + 1, P, Q); step(kk + 2, Q, P); }
    step(63, P, Q);  // k = 62, latches lane 63

    // ---- head burst: lane l handles tau = c*64 + l, y from register ysave ----
    {
      float ys[8] = {ysv[0].x, ysv[0].y, ysv[1].x, ysv[1].y,
                     ysv[2].x, ysv[2].y, ysv[3].x, ysv[3].y};
      float o0 = hw[110], o1 = hw[111];
      #pragma unroll
      for (int m = 0; m < 10; ++m) {
        float hh = hw[80 + m];
        #pragma unroll
        for (int s = 0; s < 8; ++s) hh = fmaf(ys[s], hw[s * 10 + m], hh);
        hh = fmaxf(hh, 0.0f);
        o0 = fmaf(hh, hw[90 + m * 2 + 0], o0);
        o1 = fmaf(hh, hw[90 + m * 2 + 1], o1);
      }
      out2[c * 64 + l] = make_float2(o0, o1);
    }

    xoff &= 4095;                 // wrap at the chunk boundary (odd c)
    if (more) step(0, Q, P);      // k = 63: computes y_{(c+1)*64}, latches lane 0
  }
}

extern "C" void kernel_launch(void* const* d_in, const int* in_sizes, int n_in,
                              void* d_out, int out_size, void* d_ws, size_t ws_size,
                              hipStream_t stream) {
  const float* x   = (const float*)d_in[0];
  const float* t   = (const float*)d_in[1];
  const float* y0  = (const float*)d_in[2];
  const float* Wr1 = (const float*)d_in[3];
  const float* br1 = (const float*)d_in[4];
  const float* Wr2 = (const float*)d_in[5];
  const float* br2 = (const float*)d_in[6];
  const float* W1  = (const float*)d_in[7];
  const float* b1  = (const float*)d_in[8];
  const float* W2  = (const float*)d_in[9];
  const float* b2  = (const float*)d_in[10];
  (void)in_sizes; (void)n_in; (void)out_size; (void)d_ws; (void)ws_size;

  ode_scan_kernel<<<dim3(1024), dim3(64), 0, stream>>>(x, t, y0, Wr1, br1, Wr2,
                                                       br2, W1, b1, W2, b2,
                                                       (float*)d_out);
}

// Round 5
// 798.751 us; speedup vs baseline: 1.1143x; 1.0603x over previous
//
#include <hip/hip_runtime.h>
#include <cstdint>

// ODE Euler scan: B=1024, T=4096, S=8, E=8, H=32.
// One wave per batch element; 1024 blocks x 64 threads = 1 wave/SIMD.
// Model (R6-R9): T ~= 4*N_issue + stalls; N ~75-85, stalls ~100-130 cyc/step.
// R10: squeeze emitted-inst overhead + give the scheduler independent work
// to fill stall windows:
//   - EB holds v2f e[4]: ds_read_b128 lands directly in pk operand pairs.
//   - e-seed pipeline: seeds for the NEXT step computed post-red4 (fills the
//     red4->readlane window); dot starts at 4 parallel pk_fma.
//   - deferred ysave latch: step k+1 latches step k's y (pre-update y2),
//     making the 9 latch insts chain-independent; explicit latch63 pre-head.
//   - per-chunk base offsets (xco/tco) + literal per-step offsets -> ds imm
//     folding, no per-step SALU address updates.
//   - x4-step unrolled groups for kp1 9..60.
// Arithmetic bit-identical to R9 (absmax must stay 0.125).

typedef float v2f __attribute__((ext_vector_type(2)));

#define EXP2F(v) __builtin_amdgcn_exp2f(v)
#define RCPF(v) __builtin_amdgcn_rcpf(v)

__device__ __forceinline__ v2f pk_fma(v2f a, v2f b, v2f c) {
  asm("v_pk_fma_f32 %0, %1, %2, %0" : "+v"(c) : "v"(a), "v"(b));
  return c;
}
__device__ __forceinline__ v2f pk_mul(v2f a, v2f b) {
  v2f d;
  asm("v_pk_mul_f32 %0, %1, %2" : "=v"(d) : "v"(a), "v"(b));
  return d;
}
__device__ __forceinline__ v2f pk_add(v2f a, v2f b) {
  v2f d;
  asm("v_pk_add_f32 %0, %1, %2" : "=v"(d) : "v"(a), "v"(b));
  return d;
}

// 32-lane tree reduce on 4 values at once; results valid in lane 31 (half 0)
// and lane 63 (half 1). Fused v_add_f32_dpp per stage; chains interleaved so
// each dependent same-register pair is 4 instructions apart (covers the 2
// VALU->DPP wait states). Entry s_nop 1 guards a possibly-adjacent p-fma.
__device__ __forceinline__ void red4(float& p0, float& p1, float& p2, float& p3) {
  asm volatile(
      "s_nop 1\n\t"
      "v_add_f32_dpp %0, %0, %0 row_shr:1 row_mask:0xf bank_mask:0xf bound_ctrl:0\n\t"
      "v_add_f32_dpp %1, %1, %1 row_shr:1 row_mask:0xf bank_mask:0xf bound_ctrl:0\n\t"
      "v_add_f32_dpp %2, %2, %2 row_shr:1 row_mask:0xf bank_mask:0xf bound_ctrl:0\n\t"
      "v_add_f32_dpp %3, %3, %3 row_shr:1 row_mask:0xf bank_mask:0xf bound_ctrl:0\n\t"
      "v_add_f32_dpp %0, %0, %0 row_shr:2 row_mask:0xf bank_mask:0xf bound_ctrl:0\n\t"
      "v_add_f32_dpp %1, %1, %1 row_shr:2 row_mask:0xf bank_mask:0xf bound_ctrl:0\n\t"
      "v_add_f32_dpp %2, %2, %2 row_shr:2 row_mask:0xf bank_mask:0xf bound_ctrl:0\n\t"
      "v_add_f32_dpp %3, %3, %3 row_shr:2 row_mask:0xf bank_mask:0xf bound_ctrl:0\n\t"
      "v_add_f32_dpp %0, %0, %0 row_shr:4 row_mask:0xf bank_mask:0xf bound_ctrl:0\n\t"
      "v_add_f32_dpp %1, %1, %1 row_shr:4 row_mask:0xf bank_mask:0xf bound_ctrl:0\n\t"
      "v_add_f32_dpp %2, %2, %2 row_shr:4 row_mask:0xf bank_mask:0xf bound_ctrl:0\n\t"
      "v_add_f32_dpp %3, %3, %3 row_shr:4 row_mask:0xf bank_mask:0xf bound_ctrl:0\n\t"
      "v_add_f32_dpp %0, %0, %0 row_shr:8 row_mask:0xf bank_mask:0xf bound_ctrl:0\n\t"
      "v_add_f32_dpp %1, %1, %1 row_shr:8 row_mask:0xf bank_mask:0xf bound_ctrl:0\n\t"
      "v_add_f32_dpp %2, %2, %2 row_shr:8 row_mask:0xf bank_mask:0xf bound_ctrl:0\n\t"
      "v_add_f32_dpp %3, %3, %3 row_shr:8 row_mask:0xf bank_mask:0xf bound_ctrl:0\n\t"
      "v_add_f32_dpp %0, %0, %0 row_bcast:15 row_mask:0xa bank_mask:0xf bound_ctrl:0\n\t"
      "v_add_f32_dpp %1, %1, %1 row_bcast:15 row_mask:0xa bank_mask:0xf bound_ctrl:0\n\t"
      "v_add_f32_dpp %2, %2, %2 row_bcast:15 row_mask:0xa bank_mask:0xf bound_ctrl:0\n\t"
      "v_add_f32_dpp %3, %3, %3 row_bcast:15 row_mask:0xa bank_mask:0xf bound_ctrl:0"
      : "+v"(p0), "+v"(p1), "+v"(p2), "+v"(p3));
}

__device__ __forceinline__ float rdlane(float v, int lane) {
  return __int_as_float(__builtin_amdgcn_readlane(__float_as_int(v), lane));
}

__global__ __launch_bounds__(64, 1) void ode_scan_kernel(
    const float* __restrict__ x, const float* __restrict__ t,
    const float* __restrict__ y0, const float* __restrict__ Wr1,
    const float* __restrict__ br1, const float* __restrict__ Wr2,
    const float* __restrict__ br2, const float* __restrict__ W1,
    const float* __restrict__ b1, const float* __restrict__ W2,
    const float* __restrict__ b2, float* __restrict__ out) {
  constexpr int T = 4096;

  __shared__ __align__(16) float t_lds[4096];      // t, then dt in-place
  __shared__ __align__(16) float xbuf[2 * 64 * 8]; // double-buffered x chunks
  __shared__ float hw[112];                        // W1(80) b1(10) W2(20) b2(2)

  const int l = threadIdx.x;
  const int b = blockIdx.x;
  const int j = l & 31;     // owned hidden unit
  const int half = l >> 5;
  const int sq = half * 4;  // owned s-quad (half0: s0-3, half1: s4-7)

  // ---- stage t into LDS; dt in place (single-wave DS in-order) ----
  const float4* t4 = (const float4*)t;
  #pragma unroll
  for (int it = 0; it < 16; ++it) {
    float4 v = t4[it * 64 + l];
    *(float4*)&t_lds[(it * 64 + l) * 4] = v;
  }
  for (int it = 0; it < 64; ++it) {
    int i = it * 64 + l;
    float aa = t_lds[i];
    float cc = (i < T - 1) ? t_lds[i + 1] : 0.0f;
    t_lds[i] = cc - aa;  // slot 4095 garbage; never consumed
  }

  // ---- head weights into LDS ----
  for (int v = l; v < 112; v += 64) {
    float w;
    if (v < 80) w = W1[v];
    else if (v < 90) w = b1[v - 80];
    else if (v < 110) w = W2[v - 90];
    else w = b2[v - 110];
    hw[v] = w;
  }

  // ---- per-lane weights: pk pairs over the summation index ----
  v2f wy2[4], we2[4];
  #pragma unroll
  for (int q = 0; q < 4; ++q) {
    wy2[q].x = Wr1[(2 * q) * 32 + j];
    wy2[q].y = Wr1[(2 * q + 1) * 32 + j];
    we2[q].x = Wr1[(8 + 2 * q) * 32 + j];
    we2[q].y = Wr1[(8 + 2 * q + 1) * 32 + j];
  }
  // p-fold coefficients: p_q = w2*h + br2 = fma(-2*w2, rc, w2 + br2)
  float m2w2[4], wpb[4];
  #pragma unroll
  for (int q = 0; q < 4; ++q) {
    float w = Wr2[j * 8 + sq + q];
    float bb = (j == 0) ? br2[sq + q] : 0.0f;  // lane j==0 per half carries br2
    m2w2[q] = -2.0f * w;
    wpb[q] = w + bb;
  }
  v2f br1h; br1h.x = br1[j]; br1h.y = 0.0f;

  // ---- y state as 4 pairs, replicated in all lanes; ysave latch in regs ----
  v2f y2[4], ysv[4];
  #pragma unroll
  for (int q = 0; q < 4; ++q) {
    y2[q].x = y0[b * 8 + 2 * q];
    y2[q].y = y0[b * 8 + 2 * q + 1];
    ysv[q] = y2[q];  // lane 0's tau=0 prime (other lanes latched before use)
  }

  // ---- stage x chunk 0 ----
  const float* xbase = x + (size_t)b * (T * 8);
  {
    float4 a0 = *(const float4*)&xbase[l * 8 + 0];
    float4 a1 = *(const float4*)&xbase[l * 8 + 4];
    *(float4*)&xbuf[l * 8 + 0] = a0;
    *(float4*)&xbuf[l * 8 + 4] = a1;
  }

  float2* out2 = (float2*)out + (size_t)b * T;
  const char* xb = (const char*)xbuf;
  const char* tb = (const char*)t_lds;

  // e/dt buffers: A/B manual double-buffer; ds_read destinations ARE the
  // next step's pk operands (v2f pairs, no repack).
  struct EB { v2f e[4]; float dt; };
  EB P, Q;
  *(float4*)&P.e[0] = *(const float4*)&xbuf[0];
  *(float4*)&P.e[2] = *(const float4*)&xbuf[4];
  P.dt = t_lds[0];

  // carried e-side seeds for the buffer consumed NEXT (software pipeline)
  v2f sA = pk_fma(P.e[0], we2[0], br1h);
  v2f sB = pk_mul(P.e[1], we2[1]);
  v2f sC = pk_mul(P.e[2], we2[2]);
  v2f sD = pk_mul(P.e[3], we2[3]);

  // latch: capture current y2 into lane `lane`'s ysave (pure VALU cndmask)
  auto latch = [&](int lane) {
    const bool pr = (l == lane);
    ysv[0].x = pr ? y2[0].x : ysv[0].x;
    ysv[0].y = pr ? y2[0].y : ysv[0].y;
    ysv[1].x = pr ? y2[1].x : ysv[1].x;
    ysv[1].y = pr ? y2[1].y : ysv[1].y;
    ysv[2].x = pr ? y2[2].x : ysv[2].x;
    ysv[2].y = pr ? y2[2].y : ysv[2].y;
    ysv[3].x = pr ? y2[3].x : ysv[3].x;
    ysv[3].y = pr ? y2[3].y : ysv[3].y;
  };

  // step: deferred-latches lane (kp1-1)&63 (pre-update y2 = y of prev step);
  // consumes `in` (+ carried seeds); prefetches into `o`; computes new seeds.
  auto step = [&](int kp1, EB& in, EB& o, uint32_t xbyte, uint32_t tbyte) {
    latch((kp1 - 1) & 63);

    // prefetch (lands in o's registers, consumed next step)
    *(float4*)&o.e[0] = *(const float4*)(xb + xbyte);
    *(float4*)&o.e[2] = *(const float4*)(xb + xbyte + 16);
    o.dt = *(const float*)(tb + tbyte);

    // y-chain: 4 parallel pk_fma into the seeds, 2 pk_add levels, scalar add
    v2f a0 = pk_fma(y2[0], wy2[0], sA);
    v2f a1 = pk_fma(y2[1], wy2[1], sB);
    v2f a2 = pk_fma(y2[2], wy2[2], sC);
    v2f a3 = pk_fma(y2[3], wy2[3], sD);
    v2f s01 = pk_add(a0, a1);
    v2f s23 = pk_add(a2, a3);
    v2f gsum = pk_add(s01, s23);
    float z = gsum.x + gsum.y;

    // tanh folded into p: rc = 1/(exp2(2z*log2e)+1);
    // p_q = w2q*(1-2rc) + br2q = fma(-2*w2q, rc, w2q+br2q)
    float u = EXP2F(z * 2.885390081777927f);
    float rc = RCPF(u + 1.0f);
    float p0 = fmaf(m2w2[0], rc, wpb[0]);
    float p1 = fmaf(m2w2[1], rc, wpb[1]);
    float p2 = fmaf(m2w2[2], rc, wpb[2]);
    float p3 = fmaf(m2w2[3], rc, wpb[3]);
    red4(p0, p1, p2, p3);

    // seeds for the next consume (from o; chain-independent, fills stalls)
    sA = pk_fma(o.e[0], we2[0], br1h);
    sB = pk_mul(o.e[1], we2[1]);
    sC = pk_mul(o.e[2], we2[2]);
    sD = pk_mul(o.e[3], we2[3]);

    // y_s += dt * r_s   (r via readlane -> SGPR; v_fma v,s,v)
    float dtv = in.dt;
    y2[0].x = fmaf(rdlane(p0, 31), dtv, y2[0].x);
    y2[0].y = fmaf(rdlane(p1, 31), dtv, y2[0].y);
    y2[1].x = fmaf(rdlane(p2, 31), dtv, y2[1].x);
    y2[1].y = fmaf(rdlane(p3, 31), dtv, y2[1].y);
    y2[2].x = fmaf(rdlane(p0, 63), dtv, y2[2].x);
    y2[2].y = fmaf(rdlane(p1, 63), dtv, y2[2].y);
    y2[3].x = fmaf(rdlane(p2, 63), dtv, y2[3].x);
    y2[3].y = fmaf(rdlane(p3, 63), dtv, y2[3].y);
  };

  #pragma unroll 1
  for (int c = 0; c < 64; ++c) {
    const bool more = (c < 63);
    float4 g0 = make_float4(0.f, 0.f, 0.f, 0.f), g1 = g0;
    if (more) {
      g0 = *(const float4*)&xbase[(c + 1) * 512 + l * 8 + 0];
      g1 = *(const float4*)&xbase[(c + 1) * 512 + l * 8 + 4];
    }

    const uint32_t xco = (uint32_t)(c & 1) * 2048u;
    const uint32_t tco = (uint32_t)c * 256u;

    // kp1 = 1..8 (unrolled pairs), then stage chunk c+1 (vmcnt drained)
    #pragma unroll
    for (int k = 1; k <= 7; k += 2) {
      step(k,     P, Q, xco + (uint32_t)k * 32u,       tco + (uint32_t)k * 4u);
      step(k + 1, Q, P, xco + (uint32_t)k * 32u + 32u, tco + (uint32_t)k * 4u + 4u);
    }
    if (more) {
      *(float4*)&xbuf[((c + 1) & 1) * 512 + l * 8 + 0] = g0;
      *(float4*)&xbuf[((c + 1) & 1) * 512 + l * 8 + 4] = g1;
    }

    // kp1 = 9..60 in 13 groups of 4 (imm-folded offsets within a group)
    #pragma unroll 1
    for (int g = 0; g < 13; ++g) {
      const int k = 9 + g * 4;
      const uint32_t xb4 = xco + (uint32_t)k * 32u;
      const uint32_t tb4 = tco + (uint32_t)k * 4u;
      step(k,     P, Q, xb4,       tb4);
      step(k + 1, Q, P, xb4 + 32u, tb4 + 4u);
      step(k + 2, P, Q, xb4 + 64u, tb4 + 8u);
      step(k + 3, Q, P, xb4 + 96u, tb4 + 12u);
    }

    // kp1 = 61, 62, 63
    step(61, P, Q, xco + 61u * 32u, tco + 61u * 4u);
    step(62, Q, P, xco + 62u * 32u, tco + 62u * 4u);
    step(63, P, Q, xco + 63u * 32u, tco + 63u * 4u);
    latch(63);  // head needs lane 63's snapshot before step(0)'s deferred latch

    // ---- head burst: lane l handles tau = c*64 + l, y from register ysave ----
    {
      float ys[8] = {ysv[0].x, ysv[0].y, ysv[1].x, ysv[1].y,
                     ysv[2].x, ysv[2].y, ysv[3].x, ysv[3].y};
      float o0 = hw[110], o1 = hw[111];
      #pragma unroll
      for (int m = 0; m < 10; ++m) {
        float hh = hw[80 + m];
        #pragma unroll
        for (int s = 0; s < 8; ++s) hh = fmaf(ys[s], hw[s * 10 + m], hh);
        hh = fmaxf(hh, 0.0f);
        o0 = fmaf(hh, hw[90 + m * 2 + 0], o0);
        o1 = fmaf(hh, hw[90 + m * 2 + 1], o1);
      }
      out2[c * 64 + l] = make_float2(o0, o1);
    }

    // kp1 = 0: computes y_{(c+1)*64}; its deferred latch (lane 63) repeats the
    // explicit latch63 with the same value (harmless).
    if (more) step(0, Q, P, (uint32_t)((c + 1) & 1) * 2048u, (uint32_t)(c + 1) * 256u);
  }
}

extern "C" void kernel_launch(void* const* d_in, const int* in_sizes, int n_in,
                              void* d_out, int out_size, void* d_ws, size_t ws_size,
                              hipStream_t stream) {
  const float* x   = (const float*)d_in[0];
  const float* t   = (const float*)d_in[1];
  const float* y0  = (const float*)d_in[2];
  const float* Wr1 = (const float*)d_in[3];
  const float* br1 = (const float*)d_in[4];
  const float* Wr2 = (const float*)d_in[5];
  const float* br2 = (const float*)d_in[6];
  const float* W1  = (const float*)d_in[7];
  const float* b1  = (const float*)d_in[8];
  const float* W2  = (const float*)d_in[9];
  const float* b2  = (const float*)d_in[10];
  (void)in_sizes; (void)n_in; (void)out_size; (void)d_ws; (void)ws_size;

  ode_scan_kernel<<<dim3(1024), dim3(64), 0, stream>>>(x, t, y0, Wr1, br1, Wr2,
                                                       br2, W1, b1, W2, b2,
                                                       (float*)d_out);
}

// Round 6
// 768.498 us; speedup vs baseline: 1.1581x; 1.0394x over previous
//
#include <hip/hip_runtime.h>
#include <cstdint>

// ODE Euler scan: B=1024, T=4096, S=8, E=8, H=32.
// One wave per batch element; 1024 blocks x 64 threads = 1 wave/SIMD.
// Calibrated model (R7-R10): solo wave issues 1 inst / 4 cyc;
// dur/step = 4*(VALU ~72 + DS/SALU ~5) + residual stall (~105 cyc @R10).
// VALU-busy cyc/step tracked source inst deltas exactly at 4 cyc/inst.
// R11:
//   - 2*log2e folded into wy2/we2/br1h: removes the z*k mul (-1 inst, -1
//     serial link on the z->exp2 chain).
//   - e-reads 2-AHEAD into the DEAD buffer: at call m, e[m]'s regs are dead
//     (seeds extracted at m-1), so ds_read of e[m+1] lands there. Read-to-use
//     ~550 cyc >> 120-cyc solo DS latency -> zero lgkm stall at seeds.
//     dt stays 1-ahead (VGPR path; consume-at-end has ~600 cyc slack).
// Floored blocks kept: 20-DPP red4 (4x32-lane reduce floor), 8 readlane +
// 8 fma y-update, 9-inst register latch (R7: DS-latch swap is cost-neutral).

typedef float v2f __attribute__((ext_vector_type(2)));

#define EXP2F(v) __builtin_amdgcn_exp2f(v)
#define RCPF(v) __builtin_amdgcn_rcpf(v)

__device__ __forceinline__ v2f pk_fma(v2f a, v2f b, v2f c) {
  asm("v_pk_fma_f32 %0, %1, %2, %0" : "+v"(c) : "v"(a), "v"(b));
  return c;
}
__device__ __forceinline__ v2f pk_mul(v2f a, v2f b) {
  v2f d;
  asm("v_pk_mul_f32 %0, %1, %2" : "=v"(d) : "v"(a), "v"(b));
  return d;
}
__device__ __forceinline__ v2f pk_add(v2f a, v2f b) {
  v2f d;
  asm("v_pk_add_f32 %0, %1, %2" : "=v"(d) : "v"(a), "v"(b));
  return d;
}

// 32-lane tree reduce on 4 values at once; results valid in lane 31 (half 0)
// and lane 63 (half 1). Fused v_add_f32_dpp per stage; chains interleaved so
// each dependent same-register pair is 4 instructions apart (covers the 2
// VALU->DPP wait states). Entry s_nop 1 guards a possibly-adjacent p-fma.
__device__ __forceinline__ void red4(float& p0, float& p1, float& p2, float& p3) {
  asm volatile(
      "s_nop 1\n\t"
      "v_add_f32_dpp %0, %0, %0 row_shr:1 row_mask:0xf bank_mask:0xf bound_ctrl:0\n\t"
      "v_add_f32_dpp %1, %1, %1 row_shr:1 row_mask:0xf bank_mask:0xf bound_ctrl:0\n\t"
      "v_add_f32_dpp %2, %2, %2 row_shr:1 row_mask:0xf bank_mask:0xf bound_ctrl:0\n\t"
      "v_add_f32_dpp %3, %3, %3 row_shr:1 row_mask:0xf bank_mask:0xf bound_ctrl:0\n\t"
      "v_add_f32_dpp %0, %0, %0 row_shr:2 row_mask:0xf bank_mask:0xf bound_ctrl:0\n\t"
      "v_add_f32_dpp %1, %1, %1 row_shr:2 row_mask:0xf bank_mask:0xf bound_ctrl:0\n\t"
      "v_add_f32_dpp %2, %2, %2 row_shr:2 row_mask:0xf bank_mask:0xf bound_ctrl:0\n\t"
      "v_add_f32_dpp %3, %3, %3 row_shr:2 row_mask:0xf bank_mask:0xf bound_ctrl:0\n\t"
      "v_add_f32_dpp %0, %0, %0 row_shr:4 row_mask:0xf bank_mask:0xf bound_ctrl:0\n\t"
      "v_add_f32_dpp %1, %1, %1 row_shr:4 row_mask:0xf bank_mask:0xf bound_ctrl:0\n\t"
      "v_add_f32_dpp %2, %2, %2 row_shr:4 row_mask:0xf bank_mask:0xf bound_ctrl:0\n\t"
      "v_add_f32_dpp %3, %3, %3 row_shr:4 row_mask:0xf bank_mask:0xf bound_ctrl:0\n\t"
      "v_add_f32_dpp %0, %0, %0 row_shr:8 row_mask:0xf bank_mask:0xf bound_ctrl:0\n\t"
      "v_add_f32_dpp %1, %1, %1 row_shr:8 row_mask:0xf bank_mask:0xf bound_ctrl:0\n\t"
      "v_add_f32_dpp %2, %2, %2 row_shr:8 row_mask:0xf bank_mask:0xf bound_ctrl:0\n\t"
      "v_add_f32_dpp %3, %3, %3 row_shr:8 row_mask:0xf bank_mask:0xf bound_ctrl:0\n\t"
      "v_add_f32_dpp %0, %0, %0 row_bcast:15 row_mask:0xa bank_mask:0xf bound_ctrl:0\n\t"
      "v_add_f32_dpp %1, %1, %1 row_bcast:15 row_mask:0xa bank_mask:0xf bound_ctrl:0\n\t"
      "v_add_f32_dpp %2, %2, %2 row_bcast:15 row_mask:0xa bank_mask:0xf bound_ctrl:0\n\t"
      "v_add_f32_dpp %3, %3, %3 row_bcast:15 row_mask:0xa bank_mask:0xf bound_ctrl:0"
      : "+v"(p0), "+v"(p1), "+v"(p2), "+v"(p3));
}

__device__ __forceinline__ float rdlane(float v, int lane) {
  return __int_as_float(__builtin_amdgcn_readlane(__float_as_int(v), lane));
}

__global__ __launch_bounds__(64, 1) void ode_scan_kernel(
    const float* __restrict__ x, const float* __restrict__ t,
    const float* __restrict__ y0, const float* __restrict__ Wr1,
    const float* __restrict__ br1, const float* __restrict__ Wr2,
    const float* __restrict__ br2, const float* __restrict__ W1,
    const float* __restrict__ b1, const float* __restrict__ W2,
    const float* __restrict__ b2, float* __restrict__ out) {
  constexpr int T = 4096;
  constexpr float K2L = 2.885390081777927f;  // 2*log2(e), folded into weights

  __shared__ __align__(16) float t_lds[4096];      // t, then dt in-place
  __shared__ __align__(16) float xbuf[2 * 64 * 8]; // double-buffered x chunks
  __shared__ float hw[112];                        // W1(80) b1(10) W2(20) b2(2)

  const int l = threadIdx.x;
  const int b = blockIdx.x;
  const int j = l & 31;     // owned hidden unit
  const int half = l >> 5;
  const int sq = half * 4;  // owned s-quad (half0: s0-3, half1: s4-7)

  // ---- stage t into LDS; dt in place (single-wave DS in-order) ----
  const float4* t4 = (const float4*)t;
  #pragma unroll
  for (int it = 0; it < 16; ++it) {
    float4 v = t4[it * 64 + l];
    *(float4*)&t_lds[(it * 64 + l) * 4] = v;
  }
  for (int it = 0; it < 64; ++it) {
    int i = it * 64 + l;
    float aa = t_lds[i];
    float cc = (i < T - 1) ? t_lds[i + 1] : 0.0f;
    t_lds[i] = cc - aa;  // slot 4095 garbage; never consumed
  }

  // ---- head weights into LDS ----
  for (int v = l; v < 112; v += 64) {
    float w;
    if (v < 80) w = W1[v];
    else if (v < 90) w = b1[v - 80];
    else if (v < 110) w = W2[v - 90];
    else w = b2[v - 110];
    hw[v] = w;
  }

  // ---- per-lane weights, pre-scaled by 2*log2e (z' = K2L*z; u = exp2(z')) ----
  v2f wy2[4], we2[4];
  #pragma unroll
  for (int q = 0; q < 4; ++q) {
    wy2[q].x = Wr1[(2 * q) * 32 + j] * K2L;
    wy2[q].y = Wr1[(2 * q + 1) * 32 + j] * K2L;
    we2[q].x = Wr1[(8 + 2 * q) * 32 + j] * K2L;
    we2[q].y = Wr1[(8 + 2 * q + 1) * 32 + j] * K2L;
  }
  // p-fold coefficients: p_q = w2*h + br2 = fma(-2*w2, rc, w2 + br2)
  float m2w2[4], wpb[4];
  #pragma unroll
  for (int q = 0; q < 4; ++q) {
    float w = Wr2[j * 8 + sq + q];
    float bb = (j == 0) ? br2[sq + q] : 0.0f;  // lane j==0 per half carries br2
    m2w2[q] = -2.0f * w;
    wpb[q] = w + bb;
  }
  v2f br1h; br1h.x = br1[j] * K2L; br1h.y = 0.0f;

  // ---- y state as 4 pairs, replicated in all lanes; ysave latch in regs ----
  v2f y2[4], ysv[4];
  #pragma unroll
  for (int q = 0; q < 4; ++q) {
    y2[q].x = y0[b * 8 + 2 * q];
    y2[q].y = y0[b * 8 + 2 * q + 1];
    ysv[q] = y2[q];  // lane 0's tau=0 prime (other lanes latched before use)
  }

  // ---- stage x chunk 0 ----
  const float* xbase = x + (size_t)b * (T * 8);
  {
    float4 a0 = *(const float4*)&xbase[l * 8 + 0];
    float4 a1 = *(const float4*)&xbase[l * 8 + 4];
    *(float4*)&xbuf[l * 8 + 0] = a0;
    *(float4*)&xbuf[l * 8 + 4] = a1;
  }

  float2* out2 = (float2*)out + (size_t)b * T;
  const char* xb = (const char*)xbuf;
  const char* tb = (const char*)t_lds;

  // A/B buffers. Call m: consumes A.dt (=dt[m-1]); reads dt[m] -> B.dt;
  // reads e[m+1] -> A.e (A.e=e[m-1] is DEAD: seeds extracted at call m-1);
  // seeds for call m+1 from B.e (=e[m], read at call m-1).
  struct EB { v2f e[4]; float dt; };
  EB P, Q;
  *(float4*)&P.e[0] = *(const float4*)&xbuf[0];   // e[0]
  *(float4*)&P.e[2] = *(const float4*)&xbuf[4];
  *(float4*)&Q.e[0] = *(const float4*)&xbuf[8];   // e[1]
  *(float4*)&Q.e[2] = *(const float4*)&xbuf[12];
  P.dt = t_lds[0];

  // carried e-side seeds for the NEXT consume (software pipeline): seeds_0
  v2f sA = pk_fma(P.e[0], we2[0], br1h);
  v2f sB = pk_mul(P.e[1], we2[1]);
  v2f sC = pk_mul(P.e[2], we2[2]);
  v2f sD = pk_mul(P.e[3], we2[3]);

  // latch: capture current y2 into lane `lane`'s ysave (pure VALU cndmask)
  auto latch = [&](int lane) {
    const bool pr = (l == lane);
    ysv[0].x = pr ? y2[0].x : ysv[0].x;
    ysv[0].y = pr ? y2[0].y : ysv[0].y;
    ysv[1].x = pr ? y2[1].x : ysv[1].x;
    ysv[1].y = pr ? y2[1].y : ysv[1].y;
    ysv[2].x = pr ? y2[2].x : ysv[2].x;
    ysv[2].y = pr ? y2[2].y : ysv[2].y;
    ysv[3].x = pr ? y2[3].x : ysv[3].x;
    ysv[3].y = pr ? y2[3].y : ysv[3].y;
  };

  // step call m (kp1 = m&63 by call position): deferred-latches lane
  // (kp1-1)&63; dot from carried seeds; 2-ahead e-read into A.e; 1-ahead
  // dt-read into B.dt; new seeds from B.e; y-update from A.dt.
  auto step = [&](int kp1, EB& A, EB& B, uint32_t xbyte_e, uint32_t tbyte_dt) {
    latch((kp1 - 1) & 63);

    // e[m+1] -> A.e (dead regs); dt[m] -> B.dt
    *(float4*)&A.e[0] = *(const float4*)(xb + xbyte_e);
    *(float4*)&A.e[2] = *(const float4*)(xb + xbyte_e + 16);
    B.dt = *(const float*)(tb + tbyte_dt);

    // y-chain: 4 parallel pk_fma into the seeds, 2 pk_add levels, scalar add
    v2f a0 = pk_fma(y2[0], wy2[0], sA);
    v2f a1 = pk_fma(y2[1], wy2[1], sB);
    v2f a2 = pk_fma(y2[2], wy2[2], sC);
    v2f a3 = pk_fma(y2[3], wy2[3], sD);
    v2f s01 = pk_add(a0, a1);
    v2f s23 = pk_add(a2, a3);
    v2f gsum = pk_add(s01, s23);
    float z = gsum.x + gsum.y;  // already scaled by 2*log2e

    // rc = 1/(exp2(z')+1); p_q = fma(-2*w2q, rc, w2q+br2q)
    float u = EXP2F(z);
    float rc = RCPF(u + 1.0f);
    float p0 = fmaf(m2w2[0], rc, wpb[0]);
    float p1 = fmaf(m2w2[1], rc, wpb[1]);
    float p2 = fmaf(m2w2[2], rc, wpb[2]);
    float p3 = fmaf(m2w2[3], rc, wpb[3]);
    red4(p0, p1, p2, p3);

    // seeds for the next consume (from B.e = e[m]; chain-independent)
    sA = pk_fma(B.e[0], we2[0], br1h);
    sB = pk_mul(B.e[1], we2[1]);
    sC = pk_mul(B.e[2], we2[2]);
    sD = pk_mul(B.e[3], we2[3]);

    // y_s += dt * r_s   (r via readlane -> SGPR; v_fma v,s,v)
    float dtv = A.dt;
    y2[0].x = fmaf(rdlane(p0, 31), dtv, y2[0].x);
    y2[0].y = fmaf(rdlane(p1, 31), dtv, y2[0].y);
    y2[1].x = fmaf(rdlane(p2, 31), dtv, y2[1].x);
    y2[1].y = fmaf(rdlane(p3, 31), dtv, y2[1].y);
    y2[2].x = fmaf(rdlane(p0, 63), dtv, y2[2].x);
    y2[2].y = fmaf(rdlane(p1, 63), dtv, y2[2].y);
    y2[3].x = fmaf(rdlane(p2, 63), dtv, y2[3].x);
    y2[3].y = fmaf(rdlane(p3, 63), dtv, y2[3].y);
  };

  #pragma unroll 1
  for (int c = 0; c < 64; ++c) {
    const bool more = (c < 63);
    float4 g0 = make_float4(0.f, 0.f, 0.f, 0.f), g1 = g0;
    if (more) {
      g0 = *(const float4*)&xbase[(c + 1) * 512 + l * 8 + 0];
      g1 = *(const float4*)&xbase[(c + 1) * 512 + l * 8 + 4];
    }

    const uint32_t xco  = (uint32_t)(c & 1) * 2048u;
    const uint32_t nxco = (uint32_t)((c + 1) & 1) * 2048u;
    const uint32_t tco  = (uint32_t)c * 256u;

    // kp1 = 1..8 (e-offsets kp1+1 = 2..9), then stage chunk c+1
    #pragma unroll
    for (int k = 1; k <= 7; k += 2) {
      step(k,     P, Q, xco + (uint32_t)(k + 1) * 32u, tco + (uint32_t)k * 4u);
      step(k + 1, Q, P, xco + (uint32_t)(k + 2) * 32u, tco + (uint32_t)(k + 1) * 4u);
    }
    if (more) {
      *(float4*)&xbuf[((c + 1) & 1) * 512 + l * 8 + 0] = g0;
      *(float4*)&xbuf[((c + 1) & 1) * 512 + l * 8 + 4] = g1;
    }

    // kp1 = 9..60 in 13 groups of 4 (imm-folded offsets within a group)
    #pragma unroll 1
    for (int g = 0; g < 13; ++g) {
      const int k = 9 + g * 4;
      const uint32_t xb4 = xco + (uint32_t)(k + 1) * 32u;
      const uint32_t tb4 = tco + (uint32_t)k * 4u;
      step(k,     P, Q, xb4,       tb4);
      step(k + 1, Q, P, xb4 + 32u, tb4 + 4u);
      step(k + 2, P, Q, xb4 + 64u, tb4 + 8u);
      step(k + 3, Q, P, xb4 + 96u, tb4 + 12u);
    }

    // kp1 = 61, 62, 63 (kp1=63 reads e[(c+1)*64] -> nxco slot 0)
    step(61, P, Q, xco + 62u * 32u, tco + 61u * 4u);
    step(62, Q, P, xco + 63u * 32u, tco + 62u * 4u);
    step(63, P, Q, nxco,            tco + 63u * 4u);
    latch(63);  // head needs lane 63's snapshot before step(0)'s deferred latch

    // ---- head burst: lane l handles tau = c*64 + l, y from register ysave ----
    {
      float ys[8] = {ysv[0].x, ysv[0].y, ysv[1].x, ysv[1].y,
                     ysv[2].x, ysv[2].y, ysv[3].x, ysv[3].y};
      float o0 = hw[110], o1 = hw[111];
      #pragma unroll
      for (int m = 0; m < 10; ++m) {
        float hh = hw[80 + m];
        #pragma unroll
        for (int s = 0; s < 8; ++s) hh = fmaf(ys[s], hw[s * 10 + m], hh);
        hh = fmaxf(hh, 0.0f);
        o0 = fmaf(hh, hw[90 + m * 2 + 0], o0);
        o1 = fmaf(hh, hw[90 + m * 2 + 1], o1);
      }
      out2[c * 64 + l] = make_float2(o0, o1);
    }

    // kp1 = 0: computes y_{(c+1)*64}; e-read = e[(c+1)*64 + 1] -> nxco + 32;
    // dt-read = dt[(c+1)*64]. Its deferred latch repeats latch63 (harmless).
    if (more) step(0, Q, P, nxco + 32u, (uint32_t)(c + 1) * 256u);
  }
}

extern "C" void kernel_launch(void* const* d_in, const int* in_sizes, int n_in,
                              void* d_out, int out_size, void* d_ws, size_t ws_size,
                              hipStream_t stream) {
  const float* x   = (const float*)d_in[0];
  const float* t   = (const float*)d_in[1];
  const float* y0  = (const float*)d_in[2];
  const float* Wr1 = (const float*)d_in[3];
  const float* br1 = (const float*)d_in[4];
  const float* Wr2 = (const float*)d_in[5];
  const float* br2 = (const float*)d_in[6];
  const float* W1  = (const float*)d_in[7];
  const float* b1  = (const float*)d_in[8];
  const float* W2  = (const float*)d_in[9];
  const float* b2  = (const float*)d_in[10];
  (void)in_sizes; (void)n_in; (void)out_size; (void)d_ws; (void)ws_size;

  ode_scan_kernel<<<dim3(1024), dim3(64), 0, stream>>>(x, t, y0, Wr1, br1, Wr2,
                                                       br2, W1, b1, W2, b2,
                                                       (float*)d_out);
}

// Round 8
// 758.139 us; speedup vs baseline: 1.1740x; 1.0137x over previous
//
#include <hip/hip_runtime.h>
#include <cstdint>

// ODE Euler scan: B=1024, T=4096, S=8, E=8, H=32.
// One wave per batch element; 1024 blocks x 64 threads = 1 wave/SIMD.
// Calibrated model (R7-R11): dur/step = 4*N_VALU + 4*N_other + stall.
// R11 = 663us = 388.6 cyc/step (busy 279 + other ~25 + stall ~85).
// R12: the two non-floored items:
//   - head weights hoisted to ~112 VGPRs (1 wave/SIMD -> VGPRs free to 512;
//     loaded via one-time LDS read-back to guarantee VGPR destinations, not
//     s_load->SGPR pairs which would violate the 1-SGPR-operand rule).
//     Head: per m, 4 pk_fma + hadd + max + 2 fma, zero per-chunk DS reads.
//     LDS hwp layout transposed: hwp[m*8+s] = W1[s][m] for 8B pk pairs.
//   - 8-step unrolled groups (kp1 9..56) halve branch overhead.
// Floored blocks kept: 20-DPP red4, 8 readlane + 8 fma y-update, 9-inst
// register latch (R7/R8 A/B: DS latch cost-neutral-to-worse).
// (R12 resubmission: previous round was an infra failure, no data.)

typedef float v2f __attribute__((ext_vector_type(2)));

#define EXP2F(v) __builtin_amdgcn_exp2f(v)
#define RCPF(v) __builtin_amdgcn_rcpf(v)

__device__ __forceinline__ v2f pk_fma(v2f a, v2f b, v2f c) {
  asm("v_pk_fma_f32 %0, %1, %2, %0" : "+v"(c) : "v"(a), "v"(b));
  return c;
}
__device__ __forceinline__ v2f pk_mul(v2f a, v2f b) {
  v2f d;
  asm("v_pk_mul_f32 %0, %1, %2" : "=v"(d) : "v"(a), "v"(b));
  return d;
}
__device__ __forceinline__ v2f pk_add(v2f a, v2f b) {
  v2f d;
  asm("v_pk_add_f32 %0, %1, %2" : "=v"(d) : "v"(a), "v"(b));
  return d;
}

// 32-lane tree reduce on 4 values at once; results valid in lane 31 (half 0)
// and lane 63 (half 1). Fused v_add_f32_dpp per stage; chains interleaved so
// each dependent same-register pair is 4 instructions apart (covers the 2
// VALU->DPP wait states). Entry s_nop 1 guards a possibly-adjacent p-fma.
__device__ __forceinline__ void red4(float& p0, float& p1, float& p2, float& p3) {
  asm volatile(
      "s_nop 1\n\t"
      "v_add_f32_dpp %0, %0, %0 row_shr:1 row_mask:0xf bank_mask:0xf bound_ctrl:0\n\t"
      "v_add_f32_dpp %1, %1, %1 row_shr:1 row_mask:0xf bank_mask:0xf bound_ctrl:0\n\t"
      "v_add_f32_dpp %2, %2, %2 row_shr:1 row_mask:0xf bank_mask:0xf bound_ctrl:0\n\t"
      "v_add_f32_dpp %3, %3, %3 row_shr:1 row_mask:0xf bank_mask:0xf bound_ctrl:0\n\t"
      "v_add_f32_dpp %0, %0, %0 row_shr:2 row_mask:0xf bank_mask:0xf bound_ctrl:0\n\t"
      "v_add_f32_dpp %1, %1, %1 row_shr:2 row_mask:0xf bank_mask:0xf bound_ctrl:0\n\t"
      "v_add_f32_dpp %2, %2, %2 row_shr:2 row_mask:0xf bank_mask:0xf bound_ctrl:0\n\t"
      "v_add_f32_dpp %3, %3, %3 row_shr:2 row_mask:0xf bank_mask:0xf bound_ctrl:0\n\t"
      "v_add_f32_dpp %0, %0, %0 row_shr:4 row_mask:0xf bank_mask:0xf bound_ctrl:0\n\t"
      "v_add_f32_dpp %1, %1, %1 row_shr:4 row_mask:0xf bank_mask:0xf bound_ctrl:0\n\t"
      "v_add_f32_dpp %2, %2, %2 row_shr:4 row_mask:0xf bank_mask:0xf bound_ctrl:0\n\t"
      "v_add_f32_dpp %3, %3, %3 row_shr:4 row_mask:0xf bank_mask:0xf bound_ctrl:0\n\t"
      "v_add_f32_dpp %0, %0, %0 row_shr:8 row_mask:0xf bank_mask:0xf bound_ctrl:0\n\t"
      "v_add_f32_dpp %1, %1, %1 row_shr:8 row_mask:0xf bank_mask:0xf bound_ctrl:0\n\t"
      "v_add_f32_dpp %2, %2, %2 row_shr:8 row_mask:0xf bank_mask:0xf bound_ctrl:0\n\t"
      "v_add_f32_dpp %3, %3, %3 row_shr:8 row_mask:0xf bank_mask:0xf bound_ctrl:0\n\t"
      "v_add_f32_dpp %0, %0, %0 row_bcast:15 row_mask:0xa bank_mask:0xf bound_ctrl:0\n\t"
      "v_add_f32_dpp %1, %1, %1 row_bcast:15 row_mask:0xa bank_mask:0xf bound_ctrl:0\n\t"
      "v_add_f32_dpp %2, %2, %2 row_bcast:15 row_mask:0xa bank_mask:0xf bound_ctrl:0\n\t"
      "v_add_f32_dpp %3, %3, %3 row_bcast:15 row_mask:0xa bank_mask:0xf bound_ctrl:0"
      : "+v"(p0), "+v"(p1), "+v"(p2), "+v"(p3));
}

__device__ __forceinline__ float rdlane(float v, int lane) {
  return __int_as_float(__builtin_amdgcn_readlane(__float_as_int(v), lane));
}

__global__ __launch_bounds__(64, 1) void ode_scan_kernel(
    const float* __restrict__ x, const float* __restrict__ t,
    const float* __restrict__ y0, const float* __restrict__ Wr1,
    const float* __restrict__ br1, const float* __restrict__ Wr2,
    const float* __restrict__ br2, const float* __restrict__ W1,
    const float* __restrict__ b1, const float* __restrict__ W2,
    const float* __restrict__ b2, float* __restrict__ out) {
  constexpr int T = 4096;
  constexpr float K2L = 2.885390081777927f;  // 2*log2(e), folded into weights

  __shared__ __align__(16) float t_lds[4096];      // t, then dt in-place
  __shared__ __align__(16) float xbuf[2 * 64 * 8]; // double-buffered x chunks
  __shared__ __align__(8) float hw[112];           // W1^T(80) b1(10) W2(20) b2(2)

  const int l = threadIdx.x;
  const int b = blockIdx.x;
  const int j = l & 31;     // owned hidden unit
  const int half = l >> 5;
  const int sq = half * 4;  // owned s-quad (half0: s0-3, half1: s4-7)

  // ---- stage t into LDS; dt in place (single-wave DS in-order) ----
  const float4* t4 = (const float4*)t;
  #pragma unroll
  for (int it = 0; it < 16; ++it) {
    float4 v = t4[it * 64 + l];
    *(float4*)&t_lds[(it * 64 + l) * 4] = v;
  }
  for (int it = 0; it < 64; ++it) {
    int i = it * 64 + l;
    float aa = t_lds[i];
    float cc = (i < T - 1) ? t_lds[i + 1] : 0.0f;
    t_lds[i] = cc - aa;  // slot 4095 garbage; never consumed
  }

  // ---- head weights -> LDS (transposed W1 for pk pairs) -> VGPRs ----
  // hw[m*8+s] = W1[s][m] (80), hw[80+m] = b1[m], hw[90+2m+d] = W2[m][d],
  // hw[110..111] = b2.
  for (int v = l; v < 112; v += 64) {
    float w;
    if (v < 80) w = W1[(v & 7) * 10 + (v >> 3)];
    else if (v < 90) w = b1[v - 80];
    else if (v < 110) w = W2[v - 90];
    else w = b2[v - 110];
    hw[v] = w;
  }
  // one-time read-back into VGPRs (uniform ds_read -> VGPR dest, ~112 regs;
  // free at 1 wave/SIMD). w1p[m][q] = (W1[2q][m], W1[2q+1][m]).
  v2f w1p[10][4], b1h[10], w2p[10], b2r;
  #pragma unroll
  for (int m = 0; m < 10; ++m) {
    #pragma unroll
    for (int q = 0; q < 4; ++q) w1p[m][q] = *(const v2f*)&hw[m * 8 + 2 * q];
    b1h[m].x = hw[80 + m];
    b1h[m].y = 0.0f;
    w2p[m] = *(const v2f*)&hw[90 + 2 * m];
  }
  b2r = *(const v2f*)&hw[110];

  // ---- per-lane weights, pre-scaled by 2*log2e (z' = K2L*z; u = exp2(z')) ----
  v2f wy2[4], we2[4];
  #pragma unroll
  for (int q = 0; q < 4; ++q) {
    wy2[q].x = Wr1[(2 * q) * 32 + j] * K2L;
    wy2[q].y = Wr1[(2 * q + 1) * 32 + j] * K2L;
    we2[q].x = Wr1[(8 + 2 * q) * 32 + j] * K2L;
    we2[q].y = Wr1[(8 + 2 * q + 1) * 32 + j] * K2L;
  }
  // p-fold coefficients: p_q = w2*h + br2 = fma(-2*w2, rc, w2 + br2)
  float m2w2[4], wpb[4];
  #pragma unroll
  for (int q = 0; q < 4; ++q) {
    float w = Wr2[j * 8 + sq + q];
    float bb = (j == 0) ? br2[sq + q] : 0.0f;  // lane j==0 per half carries br2
    m2w2[q] = -2.0f * w;
    wpb[q] = w + bb;
  }
  v2f br1h; br1h.x = br1[j] * K2L; br1h.y = 0.0f;

  // ---- y state as 4 pairs, replicated in all lanes; ysave latch in regs ----
  v2f y2[4], ysv[4];
  #pragma unroll
  for (int q = 0; q < 4; ++q) {
    y2[q].x = y0[b * 8 + 2 * q];
    y2[q].y = y0[b * 8 + 2 * q + 1];
    ysv[q] = y2[q];  // lane 0's tau=0 prime (other lanes latched before use)
  }

  // ---- stage x chunk 0 ----
  const float* xbase = x + (size_t)b * (T * 8);
  {
    float4 a0 = *(const float4*)&xbase[l * 8 + 0];
    float4 a1 = *(const float4*)&xbase[l * 8 + 4];
    *(float4*)&xbuf[l * 8 + 0] = a0;
    *(float4*)&xbuf[l * 8 + 4] = a1;
  }

  float2* out2 = (float2*)out + (size_t)b * T;
  const char* xb = (const char*)xbuf;
  const char* tb = (const char*)t_lds;

  // A/B buffers. Call m: consumes A.dt (=dt[m-1]); reads dt[m] -> B.dt;
  // reads e[m+1] -> A.e (A.e=e[m-1] is DEAD: seeds extracted at call m-1);
  // seeds for call m+1 from B.e (=e[m], read at call m-1).
  struct EB { v2f e[4]; float dt; };
  EB P, Q;
  *(float4*)&P.e[0] = *(const float4*)&xbuf[0];   // e[0]
  *(float4*)&P.e[2] = *(const float4*)&xbuf[4];
  *(float4*)&Q.e[0] = *(const float4*)&xbuf[8];   // e[1]
  *(float4*)&Q.e[2] = *(const float4*)&xbuf[12];
  P.dt = t_lds[0];

  // carried e-side seeds for the NEXT consume (software pipeline): seeds_0
  v2f sA = pk_fma(P.e[0], we2[0], br1h);
  v2f sB = pk_mul(P.e[1], we2[1]);
  v2f sC = pk_mul(P.e[2], we2[2]);
  v2f sD = pk_mul(P.e[3], we2[3]);

  // latch: capture current y2 into lane `lane`'s ysave (pure VALU cndmask)
  auto latch = [&](int lane) {
    const bool pr = (l == lane);
    ysv[0].x = pr ? y2[0].x : ysv[0].x;
    ysv[0].y = pr ? y2[0].y : ysv[0].y;
    ysv[1].x = pr ? y2[1].x : ysv[1].x;
    ysv[1].y = pr ? y2[1].y : ysv[1].y;
    ysv[2].x = pr ? y2[2].x : ysv[2].x;
    ysv[2].y = pr ? y2[2].y : ysv[2].y;
    ysv[3].x = pr ? y2[3].x : ysv[3].x;
    ysv[3].y = pr ? y2[3].y : ysv[3].y;
  };

  // step call m (kp1 = m&63 by call position): deferred-latches lane
  // (kp1-1)&63; dot from carried seeds; 2-ahead e-read into A.e; 1-ahead
  // dt-read into B.dt; new seeds from B.e; y-update from A.dt.
  auto step = [&](int kp1, EB& A, EB& B, uint32_t xbyte_e, uint32_t tbyte_dt) {
    latch((kp1 - 1) & 63);

    // e[m+1] -> A.e (dead regs); dt[m] -> B.dt
    *(float4*)&A.e[0] = *(const float4*)(xb + xbyte_e);
    *(float4*)&A.e[2] = *(const float4*)(xb + xbyte_e + 16);
    B.dt = *(const float*)(tb + tbyte_dt);

    // y-chain: 4 parallel pk_fma into the seeds, 2 pk_add levels, scalar add
    v2f a0 = pk_fma(y2[0], wy2[0], sA);
    v2f a1 = pk_fma(y2[1], wy2[1], sB);
    v2f a2 = pk_fma(y2[2], wy2[2], sC);
    v2f a3 = pk_fma(y2[3], wy2[3], sD);
    v2f s01 = pk_add(a0, a1);
    v2f s23 = pk_add(a2, a3);
    v2f gsum = pk_add(s01, s23);
    float z = gsum.x + gsum.y;  // already scaled by 2*log2e

    // rc = 1/(exp2(z')+1); p_q = fma(-2*w2q, rc, w2q+br2q)
    float u = EXP2F(z);
    float rc = RCPF(u + 1.0f);
    float p0 = fmaf(m2w2[0], rc, wpb[0]);
    float p1 = fmaf(m2w2[1], rc, wpb[1]);
    float p2 = fmaf(m2w2[2], rc, wpb[2]);
    float p3 = fmaf(m2w2[3], rc, wpb[3]);
    red4(p0, p1, p2, p3);

    // seeds for the next consume (from B.e = e[m]; chain-independent)
    sA = pk_fma(B.e[0], we2[0], br1h);
    sB = pk_mul(B.e[1], we2[1]);
    sC = pk_mul(B.e[2], we2[2]);
    sD = pk_mul(B.e[3], we2[3]);

    // y_s += dt * r_s   (r via readlane -> SGPR; v_fma v,s,v)
    float dtv = A.dt;
    y2[0].x = fmaf(rdlane(p0, 31), dtv, y2[0].x);
    y2[0].y = fmaf(rdlane(p1, 31), dtv, y2[0].y);
    y2[1].x = fmaf(rdlane(p2, 31), dtv, y2[1].x);
    y2[1].y = fmaf(rdlane(p3, 31), dtv, y2[1].y);
    y2[2].x = fmaf(rdlane(p0, 63), dtv, y2[2].x);
    y2[2].y = fmaf(rdlane(p1, 63), dtv, y2[2].y);
    y2[3].x = fmaf(rdlane(p2, 63), dtv, y2[3].x);
    y2[3].y = fmaf(rdlane(p3, 63), dtv, y2[3].y);
  };

  #pragma unroll 1
  for (int c = 0; c < 64; ++c) {
    const bool more = (c < 63);
    float4 g0 = make_float4(0.f, 0.f, 0.f, 0.f), g1 = g0;
    if (more) {
      g0 = *(const float4*)&xbase[(c + 1) * 512 + l * 8 + 0];
      g1 = *(const float4*)&xbase[(c + 1) * 512 + l * 8 + 4];
    }

    const uint32_t xco  = (uint32_t)(c & 1) * 2048u;
    const uint32_t nxco = (uint32_t)((c + 1) & 1) * 2048u;
    const uint32_t tco  = (uint32_t)c * 256u;

    // kp1 = 1..8 (e-offsets kp1+1 = 2..9), then stage chunk c+1
    #pragma unroll
    for (int k = 1; k <= 7; k += 2) {
      step(k,     P, Q, xco + (uint32_t)(k + 1) * 32u, tco + (uint32_t)k * 4u);
      step(k + 1, Q, P, xco + (uint32_t)(k + 2) * 32u, tco + (uint32_t)(k + 1) * 4u);
    }
    if (more) {
      *(float4*)&xbuf[((c + 1) & 1) * 512 + l * 8 + 0] = g0;
      *(float4*)&xbuf[((c + 1) & 1) * 512 + l * 8 + 4] = g1;
    }

    // kp1 = 9..56 in 6 groups of 8 (imm-folded offsets within a group)
    #pragma unroll 1
    for (int g = 0; g < 6; ++g) {
      const int k = 9 + g * 8;
      const uint32_t xb8 = xco + (uint32_t)(k + 1) * 32u;
      const uint32_t tb8 = tco + (uint32_t)k * 4u;
      step(k,     P, Q, xb8,        tb8);
      step(k + 1, Q, P, xb8 + 32u,  tb8 + 4u);
      step(k + 2, P, Q, xb8 + 64u,  tb8 + 8u);
      step(k + 3, Q, P, xb8 + 96u,  tb8 + 12u);
      step(k + 4, P, Q, xb8 + 128u, tb8 + 16u);
      step(k + 5, Q, P, xb8 + 160u, tb8 + 20u);
      step(k + 6, P, Q, xb8 + 192u, tb8 + 24u);
      step(k + 7, Q, P, xb8 + 224u, tb8 + 28u);
    }

    // kp1 = 57..63 (kp1=63 reads e[(c+1)*64] -> nxco slot 0)
    step(57, P, Q, xco + 58u * 32u, tco + 57u * 4u);
    step(58, Q, P, xco + 59u * 32u, tco + 58u * 4u);
    step(59, P, Q, xco + 60u * 32u, tco + 59u * 4u);
    step(60, Q, P, xco + 61u * 32u, tco + 60u * 4u);
    step(61, P, Q, xco + 62u * 32u, tco + 61u * 4u);
    step(62, Q, P, xco + 63u * 32u, tco + 62u * 4u);
    step(63, P, Q, nxco,            tco + 63u * 4u);
    latch(63);  // head needs lane 63's snapshot before step(0)'s deferred latch

    // ---- head burst: lane l handles tau = c*64 + l, all weights in VGPRs ----
    {
      float o0 = b2r.x, o1 = b2r.y;
      #pragma unroll
      for (int m = 0; m < 10; ++m) {
        v2f acc = pk_fma(ysv[0], w1p[m][0], b1h[m]);
        acc = pk_fma(ysv[1], w1p[m][1], acc);
        acc = pk_fma(ysv[2], w1p[m][2], acc);
        acc = pk_fma(ysv[3], w1p[m][3], acc);
        float hh = acc.x + acc.y;
        hh = fmaxf(hh, 0.0f);
        o0 = fmaf(hh, w2p[m].x, o0);
        o1 = fmaf(hh, w2p[m].y, o1);
      }
      out2[c * 64 + l] = make_float2(o0, o1);
    }

    // kp1 = 0: computes y_{(c+1)*64}; e-read = e[(c+1)*64 + 1] -> nxco + 32;
    // dt-read = dt[(c+1)*64]. Its deferred latch repeats latch63 (harmless).
    if (more) step(0, Q, P, nxco + 32u, (uint32_t)(c + 1) * 256u);
  }
}

extern "C" void kernel_launch(void* const* d_in, const int* in_sizes, int n_in,
                              void* d_out, int out_size, void* d_ws, size_t ws_size,
                              hipStream_t stream) {
  const float* x   = (const float*)d_in[0];
  const float* t   = (const float*)d_in[1];
  const float* y0  = (const float*)d_in[2];
  const float* Wr1 = (const float*)d_in[3];
  const float* br1 = (const float*)d_in[4];
  const float* Wr2 = (const float*)d_in[5];
  const float* br2 = (const float*)d_in[6];
  const float* W1  = (const float*)d_in[7];
  const float* b1  = (const float*)d_in[8];
  const float* W2  = (const float*)d_in[9];
  const float* b2  = (const float*)d_in[10];
  (void)in_sizes; (void)n_in; (void)out_size; (void)d_ws; (void)ws_size;

  ode_scan_kernel<<<dim3(1024), dim3(64), 0, stream>>>(x, t, y0, Wr1, br1, Wr2,
                                                       br2, W1, b1, W2, b2,
                                                       (float*)d_out);
}